// Round 4
// baseline (564.742 us; speedup 1.0000x reference)
//
#include <hip/hip_runtime.h>
#include <stdint.h>

typedef __bf16 bf16;
typedef unsigned char u8;
typedef __attribute__((ext_vector_type(8))) __bf16 bf16x8;
typedef __attribute__((ext_vector_type(4))) float f32x4;
typedef __attribute__((ext_vector_type(2))) float f32x2;

#define N_NODES 100000
#define F_IN 165
#define NB 391     // coarse buckets of 256 nodes
#define NBLK 320   // blocks in bucket passes

static inline int cdiv(int a, int b) { return (a + b - 1) / b; }

__device__ __forceinline__ float bfu(unsigned hw) {
  union { unsigned u; float f; } v; v.u = hw << 16; return v.f;
}
__device__ __forceinline__ unsigned packbf2(float a, float b) {
  bf16 x = (bf16)a, y = (bf16)b;
  unsigned short sx = __builtin_bit_cast(unsigned short, x);
  unsigned short sy = __builtin_bit_cast(unsigned short, y);
  return (unsigned)sx | ((unsigned)sy << 16);
}
__device__ __forceinline__ u8 f32_to_fp8(float v) {
  int t = __builtin_amdgcn_cvt_pk_fp8_f32(v, 0.f, 0, false);
  return (u8)(t & 0xff);
}

__device__ __forceinline__ void async16(const bf16* g, const bf16* l) {
  __builtin_amdgcn_global_load_lds(
      (const __attribute__((address_space(1))) void*)g,
      (__attribute__((address_space(3))) void*)l, 16, 0, 0);
}

// ---------------- edge dtype detection ----------------
__global__ void detect_k(const int* __restrict__ ei32, int* __restrict__ flag) {
  int i = blockIdx.x * 256 + threadIdx.x;
  int v = ei32[2 * i + 1];
  if (v != 0) atomicOr(flag, 1);
}

// ---------------- bucket-sort preprocessing (LDS atomics only) ------

__global__ __launch_bounds__(256) void hist_k(const int* __restrict__ ei, int E,
                                              const int* __restrict__ flag,
                                              int* __restrict__ gcd, int* __restrict__ gcs) {
  __shared__ int hd[NB], hs[NB];
  int b = blockIdx.x, t = threadIdx.x;
  for (int i = t; i < NB; i += 256) { hd[i] = 0; hs[i] = 0; }
  __syncthreads();
  int sh = (*flag) ? 0 : 1;
  int CH = (E + NBLK - 1) / NBLK;
  int lo = b * CH, hi = min(E, lo + CH);
  for (int e = lo + t; e < hi; e += 256) {
    int s = ei[(size_t)e << sh];
    int d = ei[(size_t)(E + e) << sh];
    if ((unsigned)s < (unsigned)N_NODES && (unsigned)d < (unsigned)N_NODES && s != d) {
      atomicAdd(&hd[d >> 8], 1);
      atomicAdd(&hs[s >> 8], 1);
    }
  }
  __syncthreads();
  for (int i = t; i < NB; i += 256) {
    gcd[i * NBLK + b] = hd[i];
    gcs[i * NBLK + b] = hs[i];
  }
}

// scatter dst-sorted and src-sorted entries into ONE packed buffer
// (src region offsets already include the dst-region total, via concatenated scan)
__global__ __launch_bounds__(256) void scat2_k(const int* __restrict__ ei, int E,
                                               const int* __restrict__ flag,
                                               const int* __restrict__ ofd,
                                               const int* __restrict__ ofs,
                                               unsigned* __restrict__ pkAll) {
  __shared__ int based[NB], bases[NB];
  int b = blockIdx.x, t = threadIdx.x;
  for (int i = t; i < NB; i += 256) {
    based[i] = ofd[i * NBLK + b];
    bases[i] = ofs[i * NBLK + b];
  }
  __syncthreads();
  int sh = (*flag) ? 0 : 1;
  int CH = (E + NBLK - 1) / NBLK;
  int lo = b * CH, hi = min(E, lo + CH);
  for (int e = lo + t; e < hi; e += 256) {
    int s = ei[(size_t)e << sh];
    int d = ei[(size_t)(E + e) << sh];
    if ((unsigned)s < (unsigned)N_NODES && (unsigned)d < (unsigned)N_NODES && s != d) {
      int pd = atomicAdd(&based[d >> 8], 1);
      pkAll[pd] = ((unsigned)(d & 255) << 24) | (unsigned)s;
      int ps = atomicAdd(&bases[s >> 8], 1);
      pkAll[ps] = (unsigned)s;
    }
  }
}

__global__ __launch_bounds__(256) void fin_dst_k(const unsigned* __restrict__ pk,
                                                 const int* __restrict__ ofd,
                                                 const int* __restrict__ totald,
                                                 int* __restrict__ rowptr,
                                                 int* __restrict__ csr) {
  __shared__ int fh[256], fb[256];
  int b = blockIdx.x, t = threadIdx.x;
  int lo = ofd[b * NBLK];
  int hi = (b == NB - 1) ? *totald : ofd[(b + 1) * NBLK];
  fh[t] = 0;
  __syncthreads();
  for (int i = lo + t; i < hi; i += 256) atomicAdd(&fh[pk[i] >> 24], 1);
  __syncthreads();
  fb[t] = fh[t];
  __syncthreads();
  for (int offv = 1; offv < 256; offv <<= 1) {
    int x = (t >= offv) ? fb[t - offv] : 0;
    __syncthreads();
    fb[t] += x;
    __syncthreads();
  }
  int excl = fb[t] - fh[t];
  int node = b * 256 + t;
  if (node <= N_NODES) rowptr[node] = lo + excl;
  __syncthreads();
  fb[t] = lo + excl;
  __syncthreads();
  for (int i = lo + t; i < hi; i += 256) {
    unsigned v = pk[i];
    int pos = atomicAdd(&fb[v >> 24], 1);
    csr[pos] = (int)(v & 0xFFFFFFu);
  }
}

__global__ __launch_bounds__(256) void fin_src_k(const unsigned* __restrict__ pk,
                                                 const int* __restrict__ ofs,
                                                 const int* __restrict__ grand,
                                                 float* __restrict__ dinv) {
  __shared__ int fh[256];
  int b = blockIdx.x, t = threadIdx.x;
  int lo = ofs[b * NBLK];
  int hi = (b == NB - 1) ? *grand : ofs[(b + 1) * NBLK];
  fh[t] = 0;
  __syncthreads();
  for (int i = lo + t; i < hi; i += 256) atomicAdd(&fh[pk[i] & 255], 1);
  __syncthreads();
  int node = b * 256 + t;
  if (node < N_NODES) {
    int dg = fh[t];
    dinv[node] = dg > 0 ? rsqrtf((float)dg) : 0.f;
  }
}

// ---------------- scans (concatenated, nElem up to 256*1024) ----------------

__global__ void scanA_k(const int* __restrict__ cnt, int* __restrict__ bsum, int nElem) {
  __shared__ int s[256];
  int b = blockIdx.x, t = threadIdx.x;
  int base = b * 1024;
  int sum = 0;
  for (int i = t; i < 1024; i += 256) {
    int idx = base + i;
    sum += (idx < nElem) ? cnt[idx] : 0;
  }
  s[t] = sum; __syncthreads();
  for (int off = 128; off > 0; off >>= 1) {
    if (t < off) s[t] += s[t + off];
    __syncthreads();
  }
  if (t == 0) bsum[b] = s[0];
}

__global__ void scanB_k(int* __restrict__ bsum, int* __restrict__ totalOut, int nChunk) {
  __shared__ int s[256];
  int t = threadIdx.x;  // 256
  int v = (t < nChunk) ? bsum[t] : 0;
  s[t] = v; __syncthreads();
  for (int off = 1; off < 256; off <<= 1) {
    int x = (t >= off) ? s[t - off] : 0;
    __syncthreads();
    s[t] += x;
    __syncthreads();
  }
  int excl = s[t] - v;
  if (t < nChunk) bsum[t] = excl;
  if (t == 255) *totalOut = s[255];
}

__global__ void scanC_k(const int* __restrict__ cnt, const int* __restrict__ bsum,
                        int* __restrict__ outp, int nElem) {
  __shared__ int s[256];
  int b = blockIdx.x, t = threadIdx.x;
  int base = b * 1024 + t * 4;
  int v[4]; int tot = 0;
  for (int i = 0; i < 4; i++) {
    int idx = base + i;
    v[i] = (idx < nElem) ? cnt[idx] : 0;
    tot += v[i];
  }
  s[t] = tot; __syncthreads();
  for (int off = 1; off < 256; off <<= 1) {
    int x = (t >= off) ? s[t - off] : 0;
    __syncthreads();
    s[t] += x;
    __syncthreads();
  }
  int excl = s[t] - tot + bsum[b];
  for (int i = 0; i < 4; i++) {
    int idx = base + i;
    if (idx < nElem) { outp[idx] = excl; excl += v[i]; }
  }
}

// ---------------- weight prep ----------------

// W (float): [3][Fin][128].  out (bf16): [384][Kp] = (W0-W2)^T | W1^T | (2W2)^T
__global__ void build_wct_k(const float* __restrict__ W, bf16* __restrict__ out, int Fin, int Kp) {
  int idx = blockIdx.x * 256 + threadIdx.x;
  if (idx >= 384 * Kp) return;
  int r = idx / Kp, k = idx % Kp;
  int t = r >> 7, j = r & 127;
  float v = 0.f;
  if (k < Fin) {
    if (t == 0)
      v = W[(size_t)k * 128 + j] - W[(size_t)2 * Fin * 128 + (size_t)k * 128 + j];
    else if (t == 1)
      v = W[(size_t)Fin * 128 + (size_t)k * 128 + j];
    else
      v = 2.f * W[(size_t)2 * Fin * 128 + (size_t)k * 128 + j];
  }
  out[(size_t)r * Kp + k] = (bf16)v;
}

// fused prep: wlc transposed [6][128] (t<128), fp4 pad rows (t<32), cc (wave 2)
__global__ void prep_k(const float* __restrict__ W2, const float* __restrict__ Wl,
                       const float* __restrict__ b2, const float* __restrict__ bl,
                       float* __restrict__ wlc, float* __restrict__ cc,
                       u8* __restrict__ g0, u8* __restrict__ g1) {
  int t = threadIdx.x;  // 256
  if (t < 16) ((unsigned*)(g0 + (size_t)N_NODES * 64))[t] = 0;
  else if (t < 32) ((unsigned*)(g1 + (size_t)N_NODES * 64))[t - 16] = 0;
  if (t < 128) {
    int f = t;
    float c00 = 0, c01 = 0, c10 = 0, c11 = 0, c20 = 0, c21 = 0;
    for (int k = 0; k < 128; k++) {
      float w0 = W2[(size_t)f * 128 + k];
      float w1 = W2[(size_t)128 * 128 + f * 128 + k];
      float w2 = W2[(size_t)2 * 128 * 128 + f * 128 + k];
      float l0 = Wl[k * 2], l1 = Wl[k * 2 + 1];
      c00 += (w0 - w2) * l0; c01 += (w0 - w2) * l1;
      c10 += w1 * l0;        c11 += w1 * l1;
      c20 += 2.f * w2 * l0;  c21 += 2.f * w2 * l1;
    }
    c00 += Wl[f * 2]; c01 += Wl[f * 2 + 1];
    // transposed layout: wlc[c*128 + f] so prop_k lanes read contiguous f32x4
    wlc[0 * 128 + f] = c00; wlc[1 * 128 + f] = c01;
    wlc[2 * 128 + f] = c10; wlc[3 * 128 + f] = c11;
    wlc[4 * 128 + f] = c20; wlc[5 * 128 + f] = c21;
  } else if (t < 192) {
    int c = t - 128;  // 0..63 within wave 2
    float p0 = b2[2 * c] * Wl[(2 * c) * 2] + b2[2 * c + 1] * Wl[(2 * c + 1) * 2];
    float p1 = b2[2 * c] * Wl[(2 * c) * 2 + 1] + b2[2 * c + 1] * Wl[(2 * c + 1) * 2 + 1];
#pragma unroll
    for (int off = 32; off > 0; off >>= 1) {
      p0 += __shfl_down(p0, off);
      p1 += __shfl_down(p1, off);
    }
    if (c == 0) { cc[0] = p0 + bl[0]; cc[1] = p1 + bl[1]; }
  }
}

// pad x (float [N][165]) -> xp (bf16 [N][192]); 2 features per thread
__global__ void pad_x_k(const float* __restrict__ x, bf16* __restrict__ xp) {
  int idx = blockIdx.x * 256 + threadIdx.x;
  if (idx >= N_NODES * 96) return;
  int n = idx / 96, k = (idx % 96) * 2;
  float a = (k < F_IN) ? x[(size_t)n * F_IN + k] : 0.f;
  float b = (k + 1 < F_IN) ? x[(size_t)n * F_IN + k + 1] : 0.f;
  *(unsigned*)(xp + (size_t)n * 192 + k) = packbf2(a, b);
}

// ---------------- GEMM: y=0,1 -> bf16; y=2 -> fp8(dinv[row]*val) row-major ----

__global__ __launch_bounds__(256) void gemm3_k(const bf16* __restrict__ A, int lda,
                                               const bf16* __restrict__ Bt, int K,
                                               bf16* __restrict__ C0, bf16* __restrict__ C1,
                                               u8* __restrict__ C2g,
                                               const float* __restrict__ dinv, int M) {
  __shared__ __align__(16) bf16 As[128 * 32];
  __shared__ __align__(16) bf16 Bs[128 * 32];
  const int tid = threadIdx.x;
  const int w = tid >> 6, l = tid & 63;
  const int mBase = blockIdx.x * 128;
  const int nb = blockIdx.y * 128;
  const int wm = (w >> 1) * 64, wn = (w & 1) * 64;
  const int lr = l & 15, lq = l >> 4;
  f32x4 acc[4][4] = {};
  for (int k0 = 0; k0 < K; k0 += 32) {
#pragma unroll
    for (int p = 0; p < 2; ++p) {
      int q = w * 2 + p;
      int row = q * 16 + (l >> 2);
      int seg = (l & 3) * 8;
      int ar = mBase + row; if (ar > M - 1) ar = M - 1;
      async16(A + (size_t)ar * lda + k0 + seg, &As[q * 512]);
      async16(Bt + (size_t)(nb + row) * K + k0 + seg, &Bs[q * 512]);
    }
    __syncthreads();
    bf16x8 a[4], b[4];
#pragma unroll
    for (int i = 0; i < 4; i++) a[i] = *(const bf16x8*)&As[(wm + i * 16 + lr) * 32 + lq * 8];
#pragma unroll
    for (int j = 0; j < 4; j++) b[j] = *(const bf16x8*)&Bs[(wn + j * 16 + lr) * 32 + lq * 8];
#pragma unroll
    for (int i = 0; i < 4; i++)
#pragma unroll
      for (int j = 0; j < 4; j++)
        acc[i][j] = __builtin_amdgcn_mfma_f32_16x16x32_bf16(a[i], b[j], acc[i][j], 0, 0, 0);
    __syncthreads();
  }
  if (blockIdx.y == 2) {
#pragma unroll
    for (int i = 0; i < 4; i++) {
#pragma unroll
      for (int r = 0; r < 4; r++) {
        int row = mBase + wm + i * 16 + lq * 4 + r;
        if (row < M) {
          float dv = dinv[row];
#pragma unroll
          for (int j = 0; j < 4; j++) {
            int col = wn + j * 16 + lr;
            C2g[(size_t)row * 128 + col] = f32_to_fp8(dv * acc[i][j][r]);
          }
        }
      }
    }
  } else {
    bf16* __restrict__ C = blockIdx.y ? C1 : C0;
#pragma unroll
    for (int i = 0; i < 4; i++) {
#pragma unroll
      for (int r = 0; r < 4; r++) {
        int row = mBase + wm + i * 16 + lq * 4 + r;
        if (row < M) {
#pragma unroll
          for (int j = 0; j < 4; j++) {
            int col = wn + j * 16 + lr;
            C[(size_t)row * 128 + col] = (bf16)acc[i][j][r];
          }
        }
      }
    }
  }
}

// fp8 row-major [N][128] -> fp4 [N][64B] with x2 prescale
__global__ void cvt48_k(const u8* __restrict__ g8, u8* __restrict__ g4) {
  int i = blockIdx.x * 256 + threadIdx.x;
  if (i >= N_NODES * 16) return;
  int n = i >> 4, j = i & 15;
  uint2 w = *(const uint2*)(g8 + (size_t)n * 128 + j * 8);
  auto a0 = __builtin_amdgcn_cvt_pk_f32_fp8((int)w.x, false);
  auto a1 = __builtin_amdgcn_cvt_pk_f32_fp8((int)w.x, true);
  auto a2 = __builtin_amdgcn_cvt_pk_f32_fp8((int)w.y, false);
  auto a3 = __builtin_amdgcn_cvt_pk_f32_fp8((int)w.y, true);
  unsigned u = 0;
  u = __builtin_amdgcn_cvt_scalef32_pk_fp4_f32(u, 2.f * a0[0], 2.f * a0[1], 1.f, 0);
  u = __builtin_amdgcn_cvt_scalef32_pk_fp4_f32(u, 2.f * a1[0], 2.f * a1[1], 1.f, 1);
  u = __builtin_amdgcn_cvt_scalef32_pk_fp4_f32(u, 2.f * a2[0], 2.f * a2[1], 1.f, 2);
  u = __builtin_amdgcn_cvt_scalef32_pk_fp4_f32(u, 2.f * a3[0], 2.f * a3[1], 1.f, 3);
  *(unsigned*)(g4 + (size_t)n * 64 + j * 4) = u;
}

// ---------------- fp4 sparse propagation ----------------
// Wave = 1 node. OCTET (8 lanes) per edge; lane k=lane&7 covers dwords 2k,2k+1
// (features 16k..16k+15) via one 8B load. 8 edges per chunk, 2-deep gather
// pipeline: gather of chunk i+1 and csr of chunk i+2 issue before decode of i.
// Tables store fp4(2 * dinv_src * value); consumer multiplies sums by 0.5.
// MODE 0: t = -0.5*dn*S + addA;          write fp4(2*dn*t) -> out4
// MODE 1: h = relu(-0.5*dn*S + addA + bias); fused V = h @ wlcT -> V0,V1,V2s
template <int MODE>
__global__ __launch_bounds__(256) void prop_k(const int* __restrict__ rowptr,
                                              const int* __restrict__ csr,
                                              const u8* __restrict__ g4,
                                              const float* __restrict__ dinv,
                                              const bf16* __restrict__ addA,
                                              const float* __restrict__ bias,
                                              const float* __restrict__ wlc,
                                              u8* __restrict__ out4,
                                              f32x2* __restrict__ V0,
                                              f32x2* __restrict__ V1,
                                              f32x2* __restrict__ V2s) {
  const int n = blockIdx.x * 4 + (threadIdx.x >> 6);
  const int lane = threadIdx.x & 63;
  const int o = lane >> 3, k = lane & 7;
  const unsigned kb = (unsigned)k << 3;  // byte offset of dword-pair k in a 64B row
  const int beg = rowptr[n], end = rowptr[n + 1];

  // hoisted per-node loads: latency overlaps the gather loop
  const float dn = dinv[n];
  uint4 ua0 = *(const uint4*)((const u8*)addA + (size_t)n * 256 + k * 32);
  uint4 ua1 = *(const uint4*)((const u8*)addA + (size_t)n * 256 + k * 32 + 16);
  f32x4 bqa, bqb, bqc, bqd;
  if (MODE == 1) {
    bqa = *(const f32x4*)(bias + 16 * k);
    bqb = *(const f32x4*)(bias + 16 * k + 4);
    bqc = *(const f32x4*)(bias + 16 * k + 8);
    bqd = *(const f32x4*)(bias + 16 * k + 12);
  }

  f32x2 av[8] = {};  // av[m] = {feat 16k+2m, feat 16k+2m+1}

  // 2-deep pipeline prologue
  int i0 = beg + o, i1 = beg + 8 + o;
  int c_cur = (i0 < end) ? csr[i0] : N_NODES;  // pad row = zeros
  int c_nxt = (i1 < end) ? csr[i1] : N_NODES;
  uint2 w_cur = *(const uint2*)(g4 + (((unsigned)c_cur << 6) | kb));

  for (int e0 = beg; e0 < end; e0 += 8) {
    // issue next chunk's gather + prefetch chunk-after-next's csr BEFORE decode
    uint2 w_nxt = *(const uint2*)(g4 + (((unsigned)c_nxt << 6) | kb));
    int i2 = e0 + 16 + o;
    int c2 = (i2 < end) ? csr[i2] : N_NODES;
    // decode current chunk: 8 cvt + 8 v_pk_add_f32
    av[0] += __builtin_amdgcn_cvt_scalef32_pk_f32_fp4(w_cur.x, 1.f, 0);
    av[1] += __builtin_amdgcn_cvt_scalef32_pk_f32_fp4(w_cur.x, 1.f, 1);
    av[2] += __builtin_amdgcn_cvt_scalef32_pk_f32_fp4(w_cur.x, 1.f, 2);
    av[3] += __builtin_amdgcn_cvt_scalef32_pk_f32_fp4(w_cur.x, 1.f, 3);
    av[4] += __builtin_amdgcn_cvt_scalef32_pk_f32_fp4(w_cur.y, 1.f, 0);
    av[5] += __builtin_amdgcn_cvt_scalef32_pk_f32_fp4(w_cur.y, 1.f, 1);
    av[6] += __builtin_amdgcn_cvt_scalef32_pk_f32_fp4(w_cur.y, 1.f, 2);
    av[7] += __builtin_amdgcn_cvt_scalef32_pk_f32_fp4(w_cur.y, 1.f, 3);
    w_cur = w_nxt;
    c_nxt = c2;
  }

  // reduce the 8 octets: lanes 0..7 end up with full sums
#pragma unroll
  for (int off = 32; off >= 8; off >>= 1) {
#pragma unroll
    for (int m = 0; m < 8; m++) {
      av[m].x += __shfl_down(av[m].x, off);
      av[m].y += __shfl_down(av[m].y, off);
    }
  }

  // per-node additive terms: 16 bf16 at features 16k..16k+15, packed pairs
  f32x2 yv[8];
  yv[0].x = bfu(ua0.x & 0xffffu); yv[0].y = bfu(ua0.x >> 16);
  yv[1].x = bfu(ua0.y & 0xffffu); yv[1].y = bfu(ua0.y >> 16);
  yv[2].x = bfu(ua0.z & 0xffffu); yv[2].y = bfu(ua0.z >> 16);
  yv[3].x = bfu(ua0.w & 0xffffu); yv[3].y = bfu(ua0.w >> 16);
  yv[4].x = bfu(ua1.x & 0xffffu); yv[4].y = bfu(ua1.x >> 16);
  yv[5].x = bfu(ua1.y & 0xffffu); yv[5].y = bfu(ua1.y >> 16);
  yv[6].x = bfu(ua1.z & 0xffffu); yv[6].y = bfu(ua1.z >> 16);
  yv[7].x = bfu(ua1.w & 0xffffu); yv[7].y = bfu(ua1.w >> 16);

  if (MODE == 0) {
    if (lane < 8) {
      // out = fp4(2dn * (-0.5dn*a + y)) = fp4(a*(-dn^2) + y*(2dn))
      const float m1 = -dn * dn, m2 = 2.f * dn;
      f32x2 ov[8];
#pragma unroll
      for (int m = 0; m < 8; m++) ov[m] = av[m] * m1 + yv[m] * m2;
      unsigned u0 = 0, u1 = 0;
      u0 = __builtin_amdgcn_cvt_scalef32_pk_fp4_f32(u0, ov[0].x, ov[0].y, 1.f, 0);
      u0 = __builtin_amdgcn_cvt_scalef32_pk_fp4_f32(u0, ov[1].x, ov[1].y, 1.f, 1);
      u0 = __builtin_amdgcn_cvt_scalef32_pk_fp4_f32(u0, ov[2].x, ov[2].y, 1.f, 2);
      u0 = __builtin_amdgcn_cvt_scalef32_pk_fp4_f32(u0, ov[3].x, ov[3].y, 1.f, 3);
      u1 = __builtin_amdgcn_cvt_scalef32_pk_fp4_f32(u1, ov[4].x, ov[4].y, 1.f, 0);
      u1 = __builtin_amdgcn_cvt_scalef32_pk_fp4_f32(u1, ov[5].x, ov[5].y, 1.f, 1);
      u1 = __builtin_amdgcn_cvt_scalef32_pk_fp4_f32(u1, ov[6].x, ov[6].y, 1.f, 2);
      u1 = __builtin_amdgcn_cvt_scalef32_pk_fp4_f32(u1, ov[7].x, ov[7].y, 1.f, 3);
      uint2 uu; uu.x = u0; uu.y = u1;
      *(uint2*)(out4 + (size_t)n * 64 + k * 8) = uu;
    }
  } else {
    // t = -0.5dn*a + y; h = relu(t + bias); V = h @ wlcT, packed pairs.
    // (lanes >=8 compute garbage, discarded by the 8-lane reduce + lane==0 write)
    const float s = -0.5f * dn;
    f32x2 hv[8];
#pragma unroll
    for (int m = 0; m < 8; m++) {
      f32x2 t = av[m] * s + yv[m];
      f32x2 bb;
      if (m == 0) { bb.x = bqa[0]; bb.y = bqa[1]; }
      if (m == 1) { bb.x = bqa[2]; bb.y = bqa[3]; }
      if (m == 2) { bb.x = bqb[0]; bb.y = bqb[1]; }
      if (m == 3) { bb.x = bqb[2]; bb.y = bqb[3]; }
      if (m == 4) { bb.x = bqc[0]; bb.y = bqc[1]; }
      if (m == 5) { bb.x = bqc[2]; bb.y = bqc[3]; }
      if (m == 6) { bb.x = bqd[0]; bb.y = bqd[1]; }
      if (m == 7) { bb.x = bqd[2]; bb.y = bqd[3]; }
      t += bb;
      hv[m].x = fmaxf(t.x, 0.f);
      hv[m].y = fmaxf(t.y, 0.f);
    }
    float p[6];
#pragma unroll
    for (int c = 0; c < 6; c++) {
      f32x4 wa = *(const f32x4*)(wlc + c * 128 + 16 * k);
      f32x4 wb = *(const f32x4*)(wlc + c * 128 + 16 * k + 4);
      f32x4 wc = *(const f32x4*)(wlc + c * 128 + 16 * k + 8);
      f32x4 wd = *(const f32x4*)(wlc + c * 128 + 16 * k + 12);
      f32x2 w0; w0.x = wa[0]; w0.y = wa[1];
      f32x2 w1; w1.x = wa[2]; w1.y = wa[3];
      f32x2 w2; w2.x = wb[0]; w2.y = wb[1];
      f32x2 w3; w3.x = wb[2]; w3.y = wb[3];
      f32x2 w4; w4.x = wc[0]; w4.y = wc[1];
      f32x2 w5; w5.x = wc[2]; w5.y = wc[3];
      f32x2 w6; w6.x = wd[0]; w6.y = wd[1];
      f32x2 w7; w7.x = wd[2]; w7.y = wd[3];
      f32x2 acc = hv[0] * w0;
      acc += hv[1] * w1;
      acc += hv[2] * w2;
      acc += hv[3] * w3;
      acc += hv[4] * w4;
      acc += hv[5] * w5;
      acc += hv[6] * w6;
      acc += hv[7] * w7;
      p[c] = acc.x + acc.y;
    }
#pragma unroll
    for (int off = 4; off >= 1; off >>= 1)
#pragma unroll
      for (int c = 0; c < 6; c++) p[c] += __shfl_down(p[c], off);
    if (lane == 0) {
      f32x2 v0, v1, v2;
      v0.x = p[0]; v0.y = p[1];
      v1.x = p[2]; v1.y = p[3];
      v2.x = dn * p[4]; v2.y = dn * p[5];
      V0[n] = v0; V1[n] = v1; V2s[n] = v2;
    }
  }
}

// tiny 2-feature props.
// MODE 0: tW[n] = dn * (-dn * sum(V2s[src]) + V1[n])
// MODE 1: z = -dn * sum(tW[src]) + V0[n] + cc; logits = log_softmax(z)
template <int MODE>
__global__ __launch_bounds__(256) void propT_k(const int* __restrict__ rowptr,
                                               const int* __restrict__ csr,
                                               const f32x2* __restrict__ gsrc,
                                               const float* __restrict__ dinv,
                                               const f32x2* __restrict__ addv,
                                               const float* __restrict__ cc,
                                               f32x2* __restrict__ outv,
                                               float* __restrict__ fout) {
  int n = blockIdx.x * 4 + (threadIdx.x >> 6);
  int l = threadIdx.x & 63;
  int beg = rowptr[n], end = rowptr[n + 1];
  float s0 = 0.f, s1 = 0.f;
  for (int idx = beg + l; idx < end; idx += 64) {
    f32x2 v = gsrc[csr[idx]];
    s0 += v.x;
    s1 += v.y;
  }
#pragma unroll
  for (int off = 32; off > 0; off >>= 1) {
    s0 += __shfl_down(s0, off);
    s1 += __shfl_down(s1, off);
  }
  if (l != 0) return;
  float dn = dinv[n];
  f32x2 av = addv[n];
  if (MODE == 0) {
    f32x2 t;
    t.x = dn * (-dn * s0 + av.x);
    t.y = dn * (-dn * s1 + av.y);
    outv[n] = t;
  } else {
    float z0 = -dn * s0 + av.x + cc[0];
    float z1 = -dn * s1 + av.y + cc[1];
    float m = fmaxf(z0, z1);
    float lse = m + logf(expf(z0 - m) + expf(z1 - m));
    fout[(size_t)n * 2 + 0] = z0 - lse;
    fout[(size_t)n * 2 + 1] = z1 - lse;
  }
}

// edges -> float32 output region
__global__ void copy_edges_k(const int* __restrict__ ei, const int* __restrict__ flag,
                             float* __restrict__ out, int n) {
  int i = blockIdx.x * 256 + threadIdx.x;
  if (i >= n) return;
  int sh = (*flag) ? 0 : 1;
  out[i] = (float)ei[(size_t)i << sh];
}

// ---------------- launch ----------------

extern "C" void kernel_launch(void* const* d_in, const int* in_sizes, int n_in,
                              void* d_out, int out_size, void* d_ws, size_t ws_size,
                              hipStream_t stream) {
  const float* x = (const float*)d_in[0];
  const int* ei = (const int*)d_in[1];
  const float* W1 = (const float*)d_in[2];
  const float* b1 = (const float*)d_in[3];
  const float* W2 = (const float*)d_in[4];
  const float* b2 = (const float*)d_in[5];
  const float* Wl = (const float*)d_in[6];
  const float* bl = (const float*)d_in[7];
  float* outp = (float*)d_out;

  const int N = N_NODES;
  const int E = in_sizes[1] / 2;
  const int L = NB * NBLK;          // 125120
  const int L2 = 2 * L;             // concatenated dst||src counts
  const int nChunkS = cdiv(L2, 1024);  // 245 <= 256

  char* ws = (char*)d_ws;
  size_t off = 0;
  auto alloc = [&](size_t bytes) {
    off = (off + 255) & ~(size_t)255;
    size_t o = off;
    off += bytes;
    return o;
  };
  int* flag = (int*)(ws + alloc(4));
  int* gcAll = (int*)(ws + alloc((size_t)L2 * 4));  // gcd | gcs (adjacent!)
  int* bsum = (int*)(ws + alloc(1024));
  int* grand = (int*)(ws + alloc(4));
  int* rowptr = (int*)(ws + alloc((size_t)(N + 1) * 4));
  float* dinv = (float*)(ws + alloc((size_t)N * 4));
  unsigned* pkAll = (unsigned*)(ws + alloc((size_t)2 * E * 4));
  int* csr = (int*)(ws + alloc((size_t)E * 4));
  bf16* wct1 = (bf16*)(ws + alloc((size_t)384 * 192 * 2));
  float* wlc = (float*)(ws + alloc((size_t)128 * 6 * 4));
  float* cc = (float*)(ws + alloc(8));
  bf16* xp = (bf16*)(ws + alloc((size_t)N * 192 * 2));
  bf16* U0 = (bf16*)(ws + alloc((size_t)N * 128 * 2));
  bf16* U1 = (bf16*)(ws + alloc((size_t)N * 128 * 2));
  u8* G8 = (u8*)(ws + alloc((size_t)N * 128));          // fp8 gemm slab-2 out
  u8* G0 = (u8*)(ws + alloc((size_t)(N + 1) * 64));     // fp4 tables
  u8* G1 = (u8*)(ws + alloc((size_t)(N + 1) * 64));
  f32x2* V0 = (f32x2*)(ws + alloc((size_t)N * 8));
  f32x2* V1 = (f32x2*)(ws + alloc((size_t)N * 8));
  f32x2* V2s = (f32x2*)(ws + alloc((size_t)N * 8));
  f32x2* tW = (f32x2*)(ws + alloc((size_t)N * 8));
  (void)ws_size;

  int* gcd = gcAll;
  int* gcs = gcAll + L;

  hipMemsetAsync(flag, 0, 4, stream);
  detect_k<<<256, 256, 0, stream>>>(ei, flag);

  // ---- bucket-sort CSR + degree (one concatenated scan) ----
  hist_k<<<NBLK, 256, 0, stream>>>(ei, E, flag, gcd, gcs);
  scanA_k<<<nChunkS, 256, 0, stream>>>(gcAll, bsum, L2);
  scanB_k<<<1, 256, 0, stream>>>(bsum, grand, nChunkS);
  scanC_k<<<nChunkS, 256, 0, stream>>>(gcAll, bsum, gcAll, L2);
  scat2_k<<<NBLK, 256, 0, stream>>>(ei, E, flag, gcd, gcs, pkAll);
  fin_dst_k<<<NB, 256, 0, stream>>>(pkAll, gcd, gcAll + L, rowptr, csr);
  fin_src_k<<<NB, 256, 0, stream>>>(pkAll, gcs, grand, dinv);

  prep_k<<<1, 256, 0, stream>>>(W2, Wl, b2, bl, wlc, cc, G0, G1);
  pad_x_k<<<cdiv(N * 96, 256), 256, 0, stream>>>(x, xp);
  build_wct_k<<<cdiv(384 * 192, 256), 256, 0, stream>>>(W1, wct1, F_IN, 192);

  const int gm = cdiv(N, 128);
  // layer 1: Y0 -> U0 (bf16), Y1 -> U1 (bf16), Y2 -> G8 (fp8, dinv-scaled)
  gemm3_k<<<dim3(gm, 3), 256, 0, stream>>>(xp, 192, wct1, 192, U0, U1, G8, dinv, N);
  cvt48_k<<<cdiv(N * 16, 256), 256, 0, stream>>>(G8, G0);
  // A1 (fp4) = dinv*(P(Y2)+Y1): gather G0, add U1 -> G1
  prop_k<0><<<N / 4, 256, 0, stream>>>(rowptr, csr, G0, dinv, U1, nullptr, nullptr,
                                       G1, nullptr, nullptr, nullptr);
  // h = relu(P(A1)+Y0+b1) fused with V = h@wlcT
  prop_k<1><<<N / 4, 256, 0, stream>>>(rowptr, csr, G1, dinv, U0, b1, wlc,
                                       nullptr, V0, V1, V2s);
  // tW = dinv * (P(v2) + v1)
  propT_k<0><<<N / 4, 256, 0, stream>>>(rowptr, csr, V2s, dinv, V1, nullptr, tW, nullptr);
  // logits = log_softmax(P(t) + v0 + cc)
  propT_k<1><<<N / 4, 256, 0, stream>>>(rowptr, csr, tW, dinv, V0, cc, nullptr, outp);

  copy_edges_k<<<cdiv(2 * E, 256), 256, 0, stream>>>(ei, flag, outp + (size_t)2 * N, 2 * E);
}

// Round 6
// 436.423 us; speedup vs baseline: 1.2940x; 1.2940x over previous
//
#include <hip/hip_runtime.h>
#include <stdint.h>

typedef __bf16 bf16;
typedef unsigned char u8;
typedef __attribute__((ext_vector_type(8))) __bf16 bf16x8;
typedef __attribute__((ext_vector_type(4))) float f32x4;
typedef __attribute__((ext_vector_type(2))) float f32x2;

#define N_NODES 100000
#define F_IN 165
#define NB 391     // coarse buckets of 256 nodes
#define NBLK 320   // blocks in bucket passes

static inline int cdiv(int a, int b) { return (a + b - 1) / b; }

__device__ __forceinline__ float bfu(unsigned hw) {
  union { unsigned u; float f; } v; v.u = hw << 16; return v.f;
}
__device__ __forceinline__ unsigned packbf2(float a, float b) {
  bf16 x = (bf16)a, y = (bf16)b;
  unsigned short sx = __builtin_bit_cast(unsigned short, x);
  unsigned short sy = __builtin_bit_cast(unsigned short, y);
  return (unsigned)sx | ((unsigned)sy << 16);
}
__device__ __forceinline__ u8 f32_to_fp8(float v) {
  int t = __builtin_amdgcn_cvt_pk_fp8_f32(v, 0.f, 0, false);
  return (u8)(t & 0xff);
}

__device__ __forceinline__ void async16(const bf16* g, const bf16* l) {
  __builtin_amdgcn_global_load_lds(
      (const __attribute__((address_space(1))) void*)g,
      (__attribute__((address_space(3))) void*)l, 16, 0, 0);
}

// ---------------- edge dtype detection ----------------
__global__ void detect_k(const int* __restrict__ ei32, int* __restrict__ flag) {
  int i = blockIdx.x * 256 + threadIdx.x;
  int v = ei32[2 * i + 1];
  if (v != 0) atomicOr(flag, 1);
}

// ---------------- bucket-sort preprocessing (LDS atomics only) ------

__global__ __launch_bounds__(256) void hist_k(const int* __restrict__ ei, int E,
                                              const int* __restrict__ flag,
                                              int* __restrict__ gcd, int* __restrict__ gcs) {
  __shared__ int hd[NB], hs[NB];
  int b = blockIdx.x, t = threadIdx.x;
  for (int i = t; i < NB; i += 256) { hd[i] = 0; hs[i] = 0; }
  __syncthreads();
  int sh = (*flag) ? 0 : 1;
  int CH = (E + NBLK - 1) / NBLK;
  int lo = b * CH, hi = min(E, lo + CH);
  for (int e = lo + t; e < hi; e += 256) {
    int s = ei[(size_t)e << sh];
    int d = ei[(size_t)(E + e) << sh];
    if ((unsigned)s < (unsigned)N_NODES && (unsigned)d < (unsigned)N_NODES && s != d) {
      atomicAdd(&hd[d >> 8], 1);
      atomicAdd(&hs[s >> 8], 1);
    }
  }
  __syncthreads();
  for (int i = t; i < NB; i += 256) {
    gcd[i * NBLK + b] = hd[i];
    gcs[i * NBLK + b] = hs[i];
  }
}

// scatter dst-sorted and src-sorted entries into ONE packed buffer
// (src region offsets already include the dst-region total, via concatenated scan)
__global__ __launch_bounds__(256) void scat2_k(const int* __restrict__ ei, int E,
                                               const int* __restrict__ flag,
                                               const int* __restrict__ ofd,
                                               const int* __restrict__ ofs,
                                               unsigned* __restrict__ pkAll) {
  __shared__ int based[NB], bases[NB];
  int b = blockIdx.x, t = threadIdx.x;
  for (int i = t; i < NB; i += 256) {
    based[i] = ofd[i * NBLK + b];
    bases[i] = ofs[i * NBLK + b];
  }
  __syncthreads();
  int sh = (*flag) ? 0 : 1;
  int CH = (E + NBLK - 1) / NBLK;
  int lo = b * CH, hi = min(E, lo + CH);
  for (int e = lo + t; e < hi; e += 256) {
    int s = ei[(size_t)e << sh];
    int d = ei[(size_t)(E + e) << sh];
    if ((unsigned)s < (unsigned)N_NODES && (unsigned)d < (unsigned)N_NODES && s != d) {
      int pd = atomicAdd(&based[d >> 8], 1);
      pkAll[pd] = ((unsigned)(d & 255) << 24) | (unsigned)s;
      int ps = atomicAdd(&bases[s >> 8], 1);
      pkAll[ps] = (unsigned)s;
    }
  }
}

__global__ __launch_bounds__(256) void fin_dst_k(const unsigned* __restrict__ pk,
                                                 const int* __restrict__ ofd,
                                                 const int* __restrict__ totald,
                                                 int* __restrict__ rowptr,
                                                 int* __restrict__ csr) {
  __shared__ int fh[256], fb[256];
  int b = blockIdx.x, t = threadIdx.x;
  int lo = ofd[b * NBLK];
  int hi = (b == NB - 1) ? *totald : ofd[(b + 1) * NBLK];
  fh[t] = 0;
  __syncthreads();
  for (int i = lo + t; i < hi; i += 256) atomicAdd(&fh[pk[i] >> 24], 1);
  __syncthreads();
  fb[t] = fh[t];
  __syncthreads();
  for (int offv = 1; offv < 256; offv <<= 1) {
    int x = (t >= offv) ? fb[t - offv] : 0;
    __syncthreads();
    fb[t] += x;
    __syncthreads();
  }
  int excl = fb[t] - fh[t];
  int node = b * 256 + t;
  if (node <= N_NODES) rowptr[node] = lo + excl;
  __syncthreads();
  fb[t] = lo + excl;
  __syncthreads();
  for (int i = lo + t; i < hi; i += 256) {
    unsigned v = pk[i];
    int pos = atomicAdd(&fb[v >> 24], 1);
    csr[pos] = (int)(v & 0xFFFFFFu);
  }
}

__global__ __launch_bounds__(256) void fin_src_k(const unsigned* __restrict__ pk,
                                                 const int* __restrict__ ofs,
                                                 const int* __restrict__ grand,
                                                 float* __restrict__ dinv) {
  __shared__ int fh[256];
  int b = blockIdx.x, t = threadIdx.x;
  int lo = ofs[b * NBLK];
  int hi = (b == NB - 1) ? *grand : ofs[(b + 1) * NBLK];
  fh[t] = 0;
  __syncthreads();
  for (int i = lo + t; i < hi; i += 256) atomicAdd(&fh[pk[i] & 255], 1);
  __syncthreads();
  int node = b * 256 + t;
  if (node < N_NODES) {
    int dg = fh[t];
    dinv[node] = dg > 0 ? rsqrtf((float)dg) : 0.f;
  }
}

// ---------------- scans (concatenated, nElem up to 256*1024) ----------------

__global__ void scanA_k(const int* __restrict__ cnt, int* __restrict__ bsum, int nElem) {
  __shared__ int s[256];
  int b = blockIdx.x, t = threadIdx.x;
  int base = b * 1024;
  int sum = 0;
  for (int i = t; i < 1024; i += 256) {
    int idx = base + i;
    sum += (idx < nElem) ? cnt[idx] : 0;
  }
  s[t] = sum; __syncthreads();
  for (int off = 128; off > 0; off >>= 1) {
    if (t < off) s[t] += s[t + off];
    __syncthreads();
  }
  if (t == 0) bsum[b] = s[0];
}

__global__ void scanB_k(int* __restrict__ bsum, int* __restrict__ totalOut, int nChunk) {
  __shared__ int s[256];
  int t = threadIdx.x;  // 256
  int v = (t < nChunk) ? bsum[t] : 0;
  s[t] = v; __syncthreads();
  for (int off = 1; off < 256; off <<= 1) {
    int x = (t >= off) ? s[t - off] : 0;
    __syncthreads();
    s[t] += x;
    __syncthreads();
  }
  int excl = s[t] - v;
  if (t < nChunk) bsum[t] = excl;
  if (t == 255) *totalOut = s[255];
}

__global__ void scanC_k(const int* __restrict__ cnt, const int* __restrict__ bsum,
                        int* __restrict__ outp, int nElem) {
  __shared__ int s[256];
  int b = blockIdx.x, t = threadIdx.x;
  int base = b * 1024 + t * 4;
  int v[4]; int tot = 0;
  for (int i = 0; i < 4; i++) {
    int idx = base + i;
    v[i] = (idx < nElem) ? cnt[idx] : 0;
    tot += v[i];
  }
  s[t] = tot; __syncthreads();
  for (int off = 1; off < 256; off <<= 1) {
    int x = (t >= off) ? s[t - off] : 0;
    __syncthreads();
    s[t] += x;
    __syncthreads();
  }
  int excl = s[t] - tot + bsum[b];
  for (int i = 0; i < 4; i++) {
    int idx = base + i;
    if (idx < nElem) { outp[idx] = excl; excl += v[i]; }
  }
}

// ---------------- weight prep ----------------

// W (float): [3][Fin][128].  out (bf16): [384][Kp] = (W0-W2)^T | W1^T | (2W2)^T
__global__ void build_wct_k(const float* __restrict__ W, bf16* __restrict__ out, int Fin, int Kp) {
  int idx = blockIdx.x * 256 + threadIdx.x;
  if (idx >= 384 * Kp) return;
  int r = idx / Kp, k = idx % Kp;
  int t = r >> 7, j = r & 127;
  float v = 0.f;
  if (k < Fin) {
    if (t == 0)
      v = W[(size_t)k * 128 + j] - W[(size_t)2 * Fin * 128 + (size_t)k * 128 + j];
    else if (t == 1)
      v = W[(size_t)Fin * 128 + (size_t)k * 128 + j];
    else
      v = 2.f * W[(size_t)2 * Fin * 128 + (size_t)k * 128 + j];
  }
  out[(size_t)r * Kp + k] = (bf16)v;
}

// fused prep: wlc transposed [6][128] (t<128), fp4 pad rows (t<32), cc (wave 2)
__global__ void prep_k(const float* __restrict__ W2, const float* __restrict__ Wl,
                       const float* __restrict__ b2, const float* __restrict__ bl,
                       float* __restrict__ wlc, float* __restrict__ cc,
                       u8* __restrict__ g0, u8* __restrict__ g1) {
  int t = threadIdx.x;  // 256
  if (t < 16) ((unsigned*)(g0 + (size_t)N_NODES * 64))[t] = 0;
  else if (t < 32) ((unsigned*)(g1 + (size_t)N_NODES * 64))[t - 16] = 0;
  if (t < 128) {
    int f = t;
    float c00 = 0, c01 = 0, c10 = 0, c11 = 0, c20 = 0, c21 = 0;
    for (int k = 0; k < 128; k++) {
      float w0 = W2[(size_t)f * 128 + k];
      float w1 = W2[(size_t)128 * 128 + f * 128 + k];
      float w2 = W2[(size_t)2 * 128 * 128 + f * 128 + k];
      float l0 = Wl[k * 2], l1 = Wl[k * 2 + 1];
      c00 += (w0 - w2) * l0; c01 += (w0 - w2) * l1;
      c10 += w1 * l0;        c11 += w1 * l1;
      c20 += 2.f * w2 * l0;  c21 += 2.f * w2 * l1;
    }
    c00 += Wl[f * 2]; c01 += Wl[f * 2 + 1];
    // transposed layout: wlc[c*128 + f] so prop_k lanes read contiguous f32x4
    wlc[0 * 128 + f] = c00; wlc[1 * 128 + f] = c01;
    wlc[2 * 128 + f] = c10; wlc[3 * 128 + f] = c11;
    wlc[4 * 128 + f] = c20; wlc[5 * 128 + f] = c21;
  } else if (t < 192) {
    int c = t - 128;  // 0..63 within wave 2
    float p0 = b2[2 * c] * Wl[(2 * c) * 2] + b2[2 * c + 1] * Wl[(2 * c + 1) * 2];
    float p1 = b2[2 * c] * Wl[(2 * c) * 2 + 1] + b2[2 * c + 1] * Wl[(2 * c + 1) * 2 + 1];
#pragma unroll
    for (int off = 32; off > 0; off >>= 1) {
      p0 += __shfl_down(p0, off);
      p1 += __shfl_down(p1, off);
    }
    if (c == 0) { cc[0] = p0 + bl[0]; cc[1] = p1 + bl[1]; }
  }
}

// pad x (float [N][165]) -> xp (bf16 [N][192]); 2 features per thread
__global__ void pad_x_k(const float* __restrict__ x, bf16* __restrict__ xp) {
  int idx = blockIdx.x * 256 + threadIdx.x;
  if (idx >= N_NODES * 96) return;
  int n = idx / 96, k = (idx % 96) * 2;
  float a = (k < F_IN) ? x[(size_t)n * F_IN + k] : 0.f;
  float b = (k + 1 < F_IN) ? x[(size_t)n * F_IN + k + 1] : 0.f;
  *(unsigned*)(xp + (size_t)n * 192 + k) = packbf2(a, b);
}

// ---------------- GEMM: y=0,1 -> bf16; y=2 -> fp8(dinv[row]*val) row-major ----

__global__ __launch_bounds__(256) void gemm3_k(const bf16* __restrict__ A, int lda,
                                               const bf16* __restrict__ Bt, int K,
                                               bf16* __restrict__ C0, bf16* __restrict__ C1,
                                               u8* __restrict__ C2g,
                                               const float* __restrict__ dinv, int M) {
  __shared__ __align__(16) bf16 As[128 * 32];
  __shared__ __align__(16) bf16 Bs[128 * 32];
  const int tid = threadIdx.x;
  const int w = tid >> 6, l = tid & 63;
  const int mBase = blockIdx.x * 128;
  const int nb = blockIdx.y * 128;
  const int wm = (w >> 1) * 64, wn = (w & 1) * 64;
  const int lr = l & 15, lq = l >> 4;
  f32x4 acc[4][4] = {};
  for (int k0 = 0; k0 < K; k0 += 32) {
#pragma unroll
    for (int p = 0; p < 2; ++p) {
      int q = w * 2 + p;
      int row = q * 16 + (l >> 2);
      int seg = (l & 3) * 8;
      int ar = mBase + row; if (ar > M - 1) ar = M - 1;
      async16(A + (size_t)ar * lda + k0 + seg, &As[q * 512]);
      async16(Bt + (size_t)(nb + row) * K + k0 + seg, &Bs[q * 512]);
    }
    __syncthreads();
    bf16x8 a[4], b[4];
#pragma unroll
    for (int i = 0; i < 4; i++) a[i] = *(const bf16x8*)&As[(wm + i * 16 + lr) * 32 + lq * 8];
#pragma unroll
    for (int j = 0; j < 4; j++) b[j] = *(const bf16x8*)&Bs[(wn + j * 16 + lr) * 32 + lq * 8];
#pragma unroll
    for (int i = 0; i < 4; i++)
#pragma unroll
      for (int j = 0; j < 4; j++)
        acc[i][j] = __builtin_amdgcn_mfma_f32_16x16x32_bf16(a[i], b[j], acc[i][j], 0, 0, 0);
    __syncthreads();
  }
  if (blockIdx.y == 2) {
#pragma unroll
    for (int i = 0; i < 4; i++) {
#pragma unroll
      for (int r = 0; r < 4; r++) {
        int row = mBase + wm + i * 16 + lq * 4 + r;
        if (row < M) {
          float dv = dinv[row];
#pragma unroll
          for (int j = 0; j < 4; j++) {
            int col = wn + j * 16 + lr;
            C2g[(size_t)row * 128 + col] = f32_to_fp8(dv * acc[i][j][r]);
          }
        }
      }
    }
  } else {
    bf16* __restrict__ C = blockIdx.y ? C1 : C0;
#pragma unroll
    for (int i = 0; i < 4; i++) {
#pragma unroll
      for (int r = 0; r < 4; r++) {
        int row = mBase + wm + i * 16 + lq * 4 + r;
        if (row < M) {
#pragma unroll
          for (int j = 0; j < 4; j++) {
            int col = wn + j * 16 + lr;
            C[(size_t)row * 128 + col] = (bf16)acc[i][j][r];
          }
        }
      }
    }
  }
}

// fp8 row-major [N][128] -> fp4 [N][64B] with x2 prescale
__global__ void cvt48_k(const u8* __restrict__ g8, u8* __restrict__ g4) {
  int i = blockIdx.x * 256 + threadIdx.x;
  if (i >= N_NODES * 16) return;
  int n = i >> 4, j = i & 15;
  uint2 w = *(const uint2*)(g8 + (size_t)n * 128 + j * 8);
  auto a0 = __builtin_amdgcn_cvt_pk_f32_fp8((int)w.x, false);
  auto a1 = __builtin_amdgcn_cvt_pk_f32_fp8((int)w.x, true);
  auto a2 = __builtin_amdgcn_cvt_pk_f32_fp8((int)w.y, false);
  auto a3 = __builtin_amdgcn_cvt_pk_f32_fp8((int)w.y, true);
  unsigned u = 0;
  u = __builtin_amdgcn_cvt_scalef32_pk_fp4_f32(u, 2.f * a0[0], 2.f * a0[1], 1.f, 0);
  u = __builtin_amdgcn_cvt_scalef32_pk_fp4_f32(u, 2.f * a1[0], 2.f * a1[1], 1.f, 1);
  u = __builtin_amdgcn_cvt_scalef32_pk_fp4_f32(u, 2.f * a2[0], 2.f * a2[1], 1.f, 2);
  u = __builtin_amdgcn_cvt_scalef32_pk_fp4_f32(u, 2.f * a3[0], 2.f * a3[1], 1.f, 3);
  *(unsigned*)(g4 + (size_t)n * 64 + j * 4) = u;
}

// ---------------- fp4 sparse propagation ----------------
// Wave = 1 node. Quarter-wave (16 lanes) per edge; lane j covers features 8j..8j+7
// (dword j of the 64B fp4 row). 32 edges per loop body (8 per quarter): all 8
// gathers issue back-to-back for max memory-level parallelism; next chunk's csr
// prefetched during decode. Packed f32x2 accumulate (v_pk_add_f32).
// Tables store fp4(2 * dinv_src * value); consumer multiplies sums by 0.5.
// MODE 0: t = -0.5*dn*S + addA;          write fp4(2*dn*t) -> out4
// MODE 1: h = relu(-0.5*dn*S + addA + bias); fused V = h @ wlcT -> V0,V1,V2s
template <int MODE>
__global__ __launch_bounds__(256) void prop_k(const int* __restrict__ rowptr,
                                              const int* __restrict__ csr,
                                              const u8* __restrict__ g4,
                                              const float* __restrict__ dinv,
                                              const bf16* __restrict__ addA,
                                              const float* __restrict__ bias,
                                              const float* __restrict__ wlc,
                                              u8* __restrict__ out4,
                                              f32x2* __restrict__ V0,
                                              f32x2* __restrict__ V1,
                                              f32x2* __restrict__ V2s) {
  const int n = blockIdx.x * 4 + (threadIdx.x >> 6);
  const int lane = threadIdx.x & 63;
  const int qq = lane >> 4, j = lane & 15;
  const int beg = rowptr[n], end = rowptr[n + 1];
  const unsigned jb = (unsigned)j << 2;  // byte offset of dword j within a 64B row

  // hoisted per-node loads: latency overlaps the gather loop
  const float dn = dinv[n];
  uint4 ua = *(const uint4*)(addA + (size_t)n * 128 + j * 8);
  f32x4 bq0, bq1;
  if (MODE == 1) {
    bq0 = *(const f32x4*)(bias + 8 * j);
    bq1 = *(const f32x4*)(bias + 8 * j + 4);
  }

  f32x2 av[4] = {};  // packed accumulators: av[k] = {feat 8j+2k, feat 8j+2k+1}

  // prefetch csr chunk 0 (32 edges: 8 per quarter)
  int c[8];
#pragma unroll
  for (int u = 0; u < 8; u++) {
    int iu = beg + 4 * u + qq;
    c[u] = (iu < end) ? csr[iu] : N_NODES;  // pad row = zeros
  }
  for (int e0 = beg; e0 < end; e0 += 32) {
    // all 8 gathers issue back-to-back (uniform SGPR base + 32-bit voffset)
    unsigned w[8];
#pragma unroll
    for (int u = 0; u < 8; u++)
      w[u] = *(const unsigned*)(g4 + (((unsigned)c[u] << 6) | jb));
    // prefetch next chunk's csr (independent of gathers)
#pragma unroll
    for (int u = 0; u < 8; u++) {
      int iu = e0 + 32 + 4 * u + qq;
      c[u] = (iu < end) ? csr[iu] : N_NODES;
    }
    // decode + packed accumulate: 4 cvt + 4 v_pk_add_f32 per dword
#pragma unroll
    for (int u = 0; u < 8; u++) {
      av[0] += __builtin_amdgcn_cvt_scalef32_pk_f32_fp4(w[u], 1.f, 0);
      av[1] += __builtin_amdgcn_cvt_scalef32_pk_f32_fp4(w[u], 1.f, 1);
      av[2] += __builtin_amdgcn_cvt_scalef32_pk_f32_fp4(w[u], 1.f, 2);
      av[3] += __builtin_amdgcn_cvt_scalef32_pk_f32_fp4(w[u], 1.f, 3);
    }
  }
  // reduce the 4 quarters: lanes 0..15 (qq==0) end up with full sums
#pragma unroll
  for (int off = 32; off >= 16; off >>= 1) {
#pragma unroll
    for (int k = 0; k < 4; k++) {
      av[k].x += __shfl_down(av[k].x, off);
      av[k].y += __shfl_down(av[k].y, off);
    }
  }

  // per-node additive terms: 8 bf16 at features 8j..8j+7, packed pairs
  f32x2 yv[4];
  yv[0].x = bfu(ua.x & 0xffffu); yv[0].y = bfu(ua.x >> 16);
  yv[1].x = bfu(ua.y & 0xffffu); yv[1].y = bfu(ua.y >> 16);
  yv[2].x = bfu(ua.z & 0xffffu); yv[2].y = bfu(ua.z >> 16);
  yv[3].x = bfu(ua.w & 0xffffu); yv[3].y = bfu(ua.w >> 16);

  if (MODE == 0) {
    if (qq == 0) {
      // out = fp4(2dn * (-0.5dn*a + y)) = fp4(a*(-dn^2) + y*(2dn))
      const float m1 = -dn * dn, m2 = 2.f * dn;
      f32x2 ov[4];
#pragma unroll
      for (int k = 0; k < 4; k++) ov[k] = av[k] * m1 + yv[k] * m2;
      unsigned u = 0;
      u = __builtin_amdgcn_cvt_scalef32_pk_fp4_f32(u, ov[0].x, ov[0].y, 1.f, 0);
      u = __builtin_amdgcn_cvt_scalef32_pk_fp4_f32(u, ov[1].x, ov[1].y, 1.f, 1);
      u = __builtin_amdgcn_cvt_scalef32_pk_fp4_f32(u, ov[2].x, ov[2].y, 1.f, 2);
      u = __builtin_amdgcn_cvt_scalef32_pk_fp4_f32(u, ov[3].x, ov[3].y, 1.f, 3);
      *(unsigned*)(out4 + (size_t)n * 64 + j * 4) = u;
    }
  } else {
    // t = -0.5dn*a + y; h = relu(t + bias); V = h @ wlcT, all in packed pairs.
    // (lanes >=16 compute garbage, discarded by the 16-lane reduce + lane==0 write)
    const float s = -0.5f * dn;
    f32x2 hv[4];
#pragma unroll
    for (int k = 0; k < 4; k++) {
      f32x2 t = av[k] * s + yv[k];
      f32x2 bb; bb.x = bq0[0], bb.y = bq0[1];
      if (k == 1) { bb.x = bq0[2]; bb.y = bq0[3]; }
      if (k == 2) { bb.x = bq1[0]; bb.y = bq1[1]; }
      if (k == 3) { bb.x = bq1[2]; bb.y = bq1[3]; }
      t += bb;
      hv[k].x = fmaxf(t.x, 0.f);
      hv[k].y = fmaxf(t.y, 0.f);
    }
    float p[6];
#pragma unroll
    for (int c2 = 0; c2 < 6; c2++) {
      f32x4 wa = *(const f32x4*)(wlc + c2 * 128 + 8 * j);
      f32x4 wb = *(const f32x4*)(wlc + c2 * 128 + 8 * j + 4);
      f32x2 w0; w0.x = wa[0]; w0.y = wa[1];
      f32x2 w1; w1.x = wa[2]; w1.y = wa[3];
      f32x2 w2; w2.x = wb[0]; w2.y = wb[1];
      f32x2 w3; w3.x = wb[2]; w3.y = wb[3];
      f32x2 acc = hv[0] * w0;
      acc += hv[1] * w1;
      acc += hv[2] * w2;
      acc += hv[3] * w3;
      p[c2] = acc.x + acc.y;
    }
#pragma unroll
    for (int off = 8; off >= 1; off >>= 1)
#pragma unroll
      for (int c2 = 0; c2 < 6; c2++) p[c2] += __shfl_down(p[c2], off);
    if (lane == 0) {
      f32x2 v0, v1, v2;
      v0.x = p[0]; v0.y = p[1];
      v1.x = p[2]; v1.y = p[3];
      v2.x = dn * p[4]; v2.y = dn * p[5];
      V0[n] = v0; V1[n] = v1; V2s[n] = v2;
    }
  }
}

// tiny 2-feature props.
// MODE 0: tW[n] = dn * (-dn * sum(V2s[src]) + V1[n])
// MODE 1: z = -dn * sum(tW[src]) + V0[n] + cc; logits = log_softmax(z)
template <int MODE>
__global__ __launch_bounds__(256) void propT_k(const int* __restrict__ rowptr,
                                               const int* __restrict__ csr,
                                               const f32x2* __restrict__ gsrc,
                                               const float* __restrict__ dinv,
                                               const f32x2* __restrict__ addv,
                                               const float* __restrict__ cc,
                                               f32x2* __restrict__ outv,
                                               float* __restrict__ fout) {
  int n = blockIdx.x * 4 + (threadIdx.x >> 6);
  int l = threadIdx.x & 63;
  int beg = rowptr[n], end = rowptr[n + 1];
  float s0 = 0.f, s1 = 0.f;
  for (int idx = beg + l; idx < end; idx += 64) {
    f32x2 v = gsrc[csr[idx]];
    s0 += v.x;
    s1 += v.y;
  }
#pragma unroll
  for (int off = 32; off > 0; off >>= 1) {
    s0 += __shfl_down(s0, off);
    s1 += __shfl_down(s1, off);
  }
  if (l != 0) return;
  float dn = dinv[n];
  f32x2 av = addv[n];
  if (MODE == 0) {
    f32x2 t;
    t.x = dn * (-dn * s0 + av.x);
    t.y = dn * (-dn * s1 + av.y);
    outv[n] = t;
  } else {
    float z0 = -dn * s0 + av.x + cc[0];
    float z1 = -dn * s1 + av.y + cc[1];
    float m = fmaxf(z0, z1);
    float lse = m + logf(expf(z0 - m) + expf(z1 - m));
    fout[(size_t)n * 2 + 0] = z0 - lse;
    fout[(size_t)n * 2 + 1] = z1 - lse;
  }
}

// edges -> float32 output region
__global__ void copy_edges_k(const int* __restrict__ ei, const int* __restrict__ flag,
                             float* __restrict__ out, int n) {
  int i = blockIdx.x * 256 + threadIdx.x;
  if (i >= n) return;
  int sh = (*flag) ? 0 : 1;
  out[i] = (float)ei[(size_t)i << sh];
}

// ---------------- launch ----------------

extern "C" void kernel_launch(void* const* d_in, const int* in_sizes, int n_in,
                              void* d_out, int out_size, void* d_ws, size_t ws_size,
                              hipStream_t stream) {
  const float* x = (const float*)d_in[0];
  const int* ei = (const int*)d_in[1];
  const float* W1 = (const float*)d_in[2];
  const float* b1 = (const float*)d_in[3];
  const float* W2 = (const float*)d_in[4];
  const float* b2 = (const float*)d_in[5];
  const float* Wl = (const float*)d_in[6];
  const float* bl = (const float*)d_in[7];
  float* outp = (float*)d_out;

  const int N = N_NODES;
  const int E = in_sizes[1] / 2;
  const int L = NB * NBLK;          // 125120
  const int L2 = 2 * L;             // concatenated dst||src counts
  const int nChunkS = cdiv(L2, 1024);  // 245 <= 256

  char* ws = (char*)d_ws;
  size_t off = 0;
  auto alloc = [&](size_t bytes) {
    off = (off + 255) & ~(size_t)255;
    size_t o = off;
    off += bytes;
    return o;
  };
  int* flag = (int*)(ws + alloc(4));
  int* gcAll = (int*)(ws + alloc((size_t)L2 * 4));  // gcd | gcs (adjacent!)
  int* bsum = (int*)(ws + alloc(1024));
  int* grand = (int*)(ws + alloc(4));
  int* rowptr = (int*)(ws + alloc((size_t)(N + 1) * 4));
  float* dinv = (float*)(ws + alloc((size_t)N * 4));
  unsigned* pkAll = (unsigned*)(ws + alloc((size_t)2 * E * 4));
  int* csr = (int*)(ws + alloc((size_t)E * 4));
  bf16* wct1 = (bf16*)(ws + alloc((size_t)384 * 192 * 2));
  float* wlc = (float*)(ws + alloc((size_t)128 * 6 * 4));
  float* cc = (float*)(ws + alloc(8));
  bf16* xp = (bf16*)(ws + alloc((size_t)N * 192 * 2));
  bf16* U0 = (bf16*)(ws + alloc((size_t)N * 128 * 2));
  bf16* U1 = (bf16*)(ws + alloc((size_t)N * 128 * 2));
  u8* G8 = (u8*)(ws + alloc((size_t)N * 128));          // fp8 gemm slab-2 out
  u8* G0 = (u8*)(ws + alloc((size_t)(N + 1) * 64));     // fp4 tables
  u8* G1 = (u8*)(ws + alloc((size_t)(N + 1) * 64));
  f32x2* V0 = (f32x2*)(ws + alloc((size_t)N * 8));
  f32x2* V1 = (f32x2*)(ws + alloc((size_t)N * 8));
  f32x2* V2s = (f32x2*)(ws + alloc((size_t)N * 8));
  f32x2* tW = (f32x2*)(ws + alloc((size_t)N * 8));
  (void)ws_size;

  int* gcd = gcAll;
  int* gcs = gcAll + L;

  hipMemsetAsync(flag, 0, 4, stream);
  detect_k<<<256, 256, 0, stream>>>(ei, flag);

  // ---- bucket-sort CSR + degree (one concatenated scan) ----
  hist_k<<<NBLK, 256, 0, stream>>>(ei, E, flag, gcd, gcs);
  scanA_k<<<nChunkS, 256, 0, stream>>>(gcAll, bsum, L2);
  scanB_k<<<1, 256, 0, stream>>>(bsum, grand, nChunkS);
  scanC_k<<<nChunkS, 256, 0, stream>>>(gcAll, bsum, gcAll, L2);
  scat2_k<<<NBLK, 256, 0, stream>>>(ei, E, flag, gcd, gcs, pkAll);
  fin_dst_k<<<NB, 256, 0, stream>>>(pkAll, gcd, gcAll + L, rowptr, csr);
  fin_src_k<<<NB, 256, 0, stream>>>(pkAll, gcs, grand, dinv);

  prep_k<<<1, 256, 0, stream>>>(W2, Wl, b2, bl, wlc, cc, G0, G1);
  pad_x_k<<<cdiv(N * 96, 256), 256, 0, stream>>>(x, xp);
  build_wct_k<<<cdiv(384 * 192, 256), 256, 0, stream>>>(W1, wct1, F_IN, 192);

  const int gm = cdiv(N, 128);
  // layer 1: Y0 -> U0 (bf16), Y1 -> U1 (bf16), Y2 -> G8 (fp8, dinv-scaled)
  gemm3_k<<<dim3(gm, 3), 256, 0, stream>>>(xp, 192, wct1, 192, U0, U1, G8, dinv, N);
  cvt48_k<<<cdiv(N * 16, 256), 256, 0, stream>>>(G8, G0);
  // A1 (fp4) = dinv*(P(Y2)+Y1): gather G0, add U1 -> G1
  prop_k<0><<<N / 4, 256, 0, stream>>>(rowptr, csr, G0, dinv, U1, nullptr, nullptr,
                                       G1, nullptr, nullptr, nullptr);
  // h = relu(P(A1)+Y0+b1) fused with V = h@wlcT
  prop_k<1><<<N / 4, 256, 0, stream>>>(rowptr, csr, G1, dinv, U0, b1, wlc,
                                       nullptr, V0, V1, V2s);
  // tW = dinv * (P(v2) + v1)
  propT_k<0><<<N / 4, 256, 0, stream>>>(rowptr, csr, V2s, dinv, V1, nullptr, tW, nullptr);
  // logits = log_softmax(P(t) + v0 + cc)
  propT_k<1><<<N / 4, 256, 0, stream>>>(rowptr, csr, tW, dinv, V0, cc, nullptr, outp);

  copy_edges_k<<<cdiv(2 * E, 256), 256, 0, stream>>>(ei, flag, outp + (size_t)2 * N, 2 * E);
}

// Round 10
// 403.478 us; speedup vs baseline: 1.3997x; 1.0817x over previous
//
#include <hip/hip_runtime.h>
#include <stdint.h>

typedef __bf16 bf16;
typedef unsigned char u8;
typedef __attribute__((ext_vector_type(8))) __bf16 bf16x8;
typedef __attribute__((ext_vector_type(4))) float f32x4;
typedef __attribute__((ext_vector_type(2))) float f32x2;

#define N_NODES 100000
#define F_IN 165
#define NB 391     // coarse buckets of 256 nodes
#define NBLK 320   // blocks in bucket passes

static inline int cdiv(int a, int b) { return (a + b - 1) / b; }

__device__ __forceinline__ float bfu(unsigned hw) {
  union { unsigned u; float f; } v; v.u = hw << 16; return v.f;
}
__device__ __forceinline__ unsigned packbf2(float a, float b) {
  bf16 x = (bf16)a, y = (bf16)b;
  unsigned short sx = __builtin_bit_cast(unsigned short, x);
  unsigned short sy = __builtin_bit_cast(unsigned short, y);
  return (unsigned)sx | ((unsigned)sy << 16);
}
__device__ __forceinline__ u8 f32_to_fp8(float v) {
  int t = __builtin_amdgcn_cvt_pk_fp8_f32(v, 0.f, 0, false);
  return (u8)(t & 0xff);
}

__device__ __forceinline__ void async16(const bf16* g, const bf16* l) {
  __builtin_amdgcn_global_load_lds(
      (const __attribute__((address_space(1))) void*)g,
      (__attribute__((address_space(3))) void*)l, 16, 0, 0);
}

// ---------------- edge dtype detection ----------------
__global__ void detect_k(const int* __restrict__ ei32, int* __restrict__ flag) {
  int i = blockIdx.x * 256 + threadIdx.x;
  int v = ei32[2 * i + 1];
  if (v != 0) atomicOr(flag, 1);
}

// ---------------- bucket-sort preprocessing (LDS atomics only) ------

__global__ __launch_bounds__(256) void hist_k(const int* __restrict__ ei, int E,
                                              const int* __restrict__ flag,
                                              int* __restrict__ gcd, int* __restrict__ gcs) {
  __shared__ int hd[NB], hs[NB];
  int b = blockIdx.x, t = threadIdx.x;
  for (int i = t; i < NB; i += 256) { hd[i] = 0; hs[i] = 0; }
  __syncthreads();
  int sh = (*flag) ? 0 : 1;
  int CH = (E + NBLK - 1) / NBLK;
  int lo = b * CH, hi = min(E, lo + CH);
  for (int e = lo + t; e < hi; e += 256) {
    int s = ei[(size_t)e << sh];
    int d = ei[(size_t)(E + e) << sh];
    if ((unsigned)s < (unsigned)N_NODES && (unsigned)d < (unsigned)N_NODES && s != d) {
      atomicAdd(&hd[d >> 8], 1);
      atomicAdd(&hs[s >> 8], 1);
    }
  }
  __syncthreads();
  for (int i = t; i < NB; i += 256) {
    gcd[i * NBLK + b] = hd[i];
    gcs[i * NBLK + b] = hs[i];
  }
}

// scatter dst-sorted and src-sorted entries into ONE packed buffer;
// ALSO emits the float-converted edge list (fused former copy_edges_k).
__global__ __launch_bounds__(256) void scat2_k(const int* __restrict__ ei, int E,
                                               const int* __restrict__ flag,
                                               const int* __restrict__ ofd,
                                               const int* __restrict__ ofs,
                                               unsigned* __restrict__ pkAll,
                                               float* __restrict__ eout) {
  __shared__ int based[NB], bases[NB];
  int b = blockIdx.x, t = threadIdx.x;
  for (int i = t; i < NB; i += 256) {
    based[i] = ofd[i * NBLK + b];
    bases[i] = ofs[i * NBLK + b];
  }
  __syncthreads();
  int sh = (*flag) ? 0 : 1;
  int CH = (E + NBLK - 1) / NBLK;
  int lo = b * CH, hi = min(E, lo + CH);
  for (int e = lo + t; e < hi; e += 256) {
    int s = ei[(size_t)e << sh];
    int d = ei[(size_t)(E + e) << sh];
    eout[e] = (float)s;
    eout[E + e] = (float)d;
    if ((unsigned)s < (unsigned)N_NODES && (unsigned)d < (unsigned)N_NODES && s != d) {
      int pd = atomicAdd(&based[d >> 8], 1);
      pkAll[pd] = ((unsigned)(d & 255) << 24) | (unsigned)s;
      int ps = atomicAdd(&bases[s >> 8], 1);
      pkAll[ps] = (unsigned)s;
    }
  }
}

__global__ __launch_bounds__(256) void fin_dst_k(const unsigned* __restrict__ pk,
                                                 const int* __restrict__ ofd,
                                                 const int* __restrict__ totald,
                                                 int* __restrict__ rowptr,
                                                 int* __restrict__ csr) {
  __shared__ int fh[256], fb[256];
  int b = blockIdx.x, t = threadIdx.x;
  int lo = ofd[b * NBLK];
  int hi = (b == NB - 1) ? *totald : ofd[(b + 1) * NBLK];
  fh[t] = 0;
  __syncthreads();
  for (int i = lo + t; i < hi; i += 256) atomicAdd(&fh[pk[i] >> 24], 1);
  __syncthreads();
  fb[t] = fh[t];
  __syncthreads();
  for (int offv = 1; offv < 256; offv <<= 1) {
    int x = (t >= offv) ? fb[t - offv] : 0;
    __syncthreads();
    fb[t] += x;
    __syncthreads();
  }
  int excl = fb[t] - fh[t];
  int node = b * 256 + t;
  if (node <= N_NODES) rowptr[node] = lo + excl;
  __syncthreads();
  fb[t] = lo + excl;
  __syncthreads();
  for (int i = lo + t; i < hi; i += 256) {
    unsigned v = pk[i];
    int pos = atomicAdd(&fb[v >> 24], 1);
    csr[pos] = (int)(v & 0xFFFFFFu);
  }
}

__global__ __launch_bounds__(256) void fin_src_k(const unsigned* __restrict__ pk,
                                                 const int* __restrict__ ofs,
                                                 const int* __restrict__ grand,
                                                 float* __restrict__ dinv) {
  __shared__ int fh[256];
  int b = blockIdx.x, t = threadIdx.x;
  int lo = ofs[b * NBLK];
  int hi = (b == NB - 1) ? *grand : ofs[(b + 1) * NBLK];
  fh[t] = 0;
  __syncthreads();
  for (int i = lo + t; i < hi; i += 256) atomicAdd(&fh[pk[i] & 255], 1);
  __syncthreads();
  int node = b * 256 + t;
  if (node < N_NODES) {
    int dg = fh[t];
    dinv[node] = dg > 0 ? rsqrtf((float)dg) : 0.f;
  }
}

// ---------------- scans (concatenated, nElem up to 256*1024) ----------------

__global__ void scanA_k(const int* __restrict__ cnt, int* __restrict__ bsum, int nElem) {
  __shared__ int s[256];
  int b = blockIdx.x, t = threadIdx.x;
  int base = b * 1024;
  int sum = 0;
  for (int i = t; i < 1024; i += 256) {
    int idx = base + i;
    sum += (idx < nElem) ? cnt[idx] : 0;
  }
  s[t] = sum; __syncthreads();
  for (int off = 128; off > 0; off >>= 1) {
    if (t < off) s[t] += s[t + off];
    __syncthreads();
  }
  if (t == 0) bsum[b] = s[0];
}

__global__ void scanB_k(int* __restrict__ bsum, int* __restrict__ totalOut, int nChunk) {
  __shared__ int s[256];
  int t = threadIdx.x;  // 256
  int v = (t < nChunk) ? bsum[t] : 0;
  s[t] = v; __syncthreads();
  for (int off = 1; off < 256; off <<= 1) {
    int x = (t >= off) ? s[t - off] : 0;
    __syncthreads();
    s[t] += x;
    __syncthreads();
  }
  int excl = s[t] - v;
  if (t < nChunk) bsum[t] = excl;
  if (t == 255) *totalOut = s[255];
}

__global__ void scanC_k(const int* __restrict__ cnt, const int* __restrict__ bsum,
                        int* __restrict__ outp, int nElem) {
  __shared__ int s[256];
  int b = blockIdx.x, t = threadIdx.x;
  int base = b * 1024 + t * 4;
  int v[4]; int tot = 0;
  for (int i = 0; i < 4; i++) {
    int idx = base + i;
    v[i] = (idx < nElem) ? cnt[idx] : 0;
    tot += v[i];
  }
  s[t] = tot; __syncthreads();
  for (int off = 1; off < 256; off <<= 1) {
    int x = (t >= off) ? s[t - off] : 0;
    __syncthreads();
    s[t] += x;
    __syncthreads();
  }
  int excl = s[t] - tot + bsum[b];
  for (int i = 0; i < 4; i++) {
    int idx = base + i;
    if (idx < nElem) { outp[idx] = excl; excl += v[i]; }
  }
}

// ---------------- weight prep ----------------

// W (float): [3][Fin][128].  out (bf16): [384][Kp] = (W0-W2)^T | W1^T | (2W2)^T
__global__ void build_wct_k(const float* __restrict__ W, bf16* __restrict__ out, int Fin, int Kp) {
  int idx = blockIdx.x * 256 + threadIdx.x;
  if (idx >= 384 * Kp) return;
  int r = idx / Kp, k = idx % Kp;
  int t = r >> 7, j = r & 127;
  float v = 0.f;
  if (k < Fin) {
    if (t == 0)
      v = W[(size_t)k * 128 + j] - W[(size_t)2 * Fin * 128 + (size_t)k * 128 + j];
    else if (t == 1)
      v = W[(size_t)Fin * 128 + (size_t)k * 128 + j];
    else
      v = 2.f * W[(size_t)2 * Fin * 128 + (size_t)k * 128 + j];
  }
  out[(size_t)r * Kp + k] = (bf16)v;
}

// fused prep: wlc transposed [6][128] (t<128), fp4 pad rows (t<32), cc (wave 2)
__global__ void prep_k(const float* __restrict__ W2, const float* __restrict__ Wl,
                       const float* __restrict__ b2, const float* __restrict__ bl,
                       float* __restrict__ wlc, float* __restrict__ cc,
                       u8* __restrict__ g0, u8* __restrict__ g1) {
  int t = threadIdx.x;  // 256
  if (t < 16) ((unsigned*)(g0 + (size_t)N_NODES * 64))[t] = 0;
  else if (t < 32) ((unsigned*)(g1 + (size_t)N_NODES * 64))[t - 16] = 0;
  if (t < 128) {
    int f = t;
    float c00 = 0, c01 = 0, c10 = 0, c11 = 0, c20 = 0, c21 = 0;
    for (int k = 0; k < 128; k++) {
      float w0 = W2[(size_t)f * 128 + k];
      float w1 = W2[(size_t)128 * 128 + f * 128 + k];
      float w2 = W2[(size_t)2 * 128 * 128 + f * 128 + k];
      float l0 = Wl[k * 2], l1 = Wl[k * 2 + 1];
      c00 += (w0 - w2) * l0; c01 += (w0 - w2) * l1;
      c10 += w1 * l0;        c11 += w1 * l1;
      c20 += 2.f * w2 * l0;  c21 += 2.f * w2 * l1;
    }
    c00 += Wl[f * 2]; c01 += Wl[f * 2 + 1];
    // transposed layout: wlc[c*128 + f] so prop_k lanes read contiguous f32x4
    wlc[0 * 128 + f] = c00; wlc[1 * 128 + f] = c01;
    wlc[2 * 128 + f] = c10; wlc[3 * 128 + f] = c11;
    wlc[4 * 128 + f] = c20; wlc[5 * 128 + f] = c21;
  } else if (t < 192) {
    int c = t - 128;  // 0..63 within wave 2
    float p0 = b2[2 * c] * Wl[(2 * c) * 2] + b2[2 * c + 1] * Wl[(2 * c + 1) * 2];
    float p1 = b2[2 * c] * Wl[(2 * c) * 2 + 1] + b2[2 * c + 1] * Wl[(2 * c + 1) * 2 + 1];
#pragma unroll
    for (int off = 32; off > 0; off >>= 1) {
      p0 += __shfl_down(p0, off);
      p1 += __shfl_down(p1, off);
    }
    if (c == 0) { cc[0] = p0 + bl[0]; cc[1] = p1 + bl[1]; }
  }
}

// pad x (float [N][165]) -> xp (bf16 [N][192]); 2 features per thread
__global__ void pad_x_k(const float* __restrict__ x, bf16* __restrict__ xp) {
  int idx = blockIdx.x * 256 + threadIdx.x;
  if (idx >= N_NODES * 96) return;
  int n = idx / 96, k = (idx % 96) * 2;
  float a = (k < F_IN) ? x[(size_t)n * F_IN + k] : 0.f;
  float b = (k + 1 < F_IN) ? x[(size_t)n * F_IN + k + 1] : 0.f;
  *(unsigned*)(xp + (size_t)n * 192 + k) = packbf2(a, b);
}

// ---------------- GEMM: y=0,1 -> bf16; y=2 -> fp8(dinv[row]*val) row-major ----
// 1-D grid with XCD co-scheduling: the 3 y-slabs of one m-tile decode to the
// SAME xcd (b&7) at consecutive k -> A-tile stays L2-hot for slabs 1,2.
// Grid = (cdiv(gm,8)*8) * 3; blocks with m >= gm return early.

__global__ __launch_bounds__(256) void gemm3_k(const bf16* __restrict__ A, int lda,
                                               const bf16* __restrict__ Bt, int K,
                                               bf16* __restrict__ C0, bf16* __restrict__ C1,
                                               u8* __restrict__ C2g,
                                               const float* __restrict__ dinv, int M) {
  __shared__ __align__(16) bf16 As[128 * 32];
  __shared__ __align__(16) bf16 Bs[128 * 32];
  const int b = blockIdx.x;
  const int xcd = b & 7, kk = b >> 3;
  const int y = kk % 3;
  const int m = xcd + 8 * (kk / 3);
  const int gmv = (M + 127) >> 7;
  if (m >= gmv) return;
  const int tid = threadIdx.x;
  const int w = tid >> 6, l = tid & 63;
  const int mBase = m * 128;
  const int nb = y * 128;
  const int wm = (w >> 1) * 64, wn = (w & 1) * 64;
  const int lr = l & 15, lq = l >> 4;
  f32x4 acc[4][4] = {};
  for (int k0 = 0; k0 < K; k0 += 32) {
#pragma unroll
    for (int p = 0; p < 2; ++p) {
      int q = w * 2 + p;
      int row = q * 16 + (l >> 2);
      int seg = (l & 3) * 8;
      int ar = mBase + row; if (ar > M - 1) ar = M - 1;
      async16(A + (size_t)ar * lda + k0 + seg, &As[q * 512]);
      async16(Bt + (size_t)(nb + row) * K + k0 + seg, &Bs[q * 512]);
    }
    __syncthreads();
    bf16x8 a[4], bb[4];
#pragma unroll
    for (int i = 0; i < 4; i++) a[i] = *(const bf16x8*)&As[(wm + i * 16 + lr) * 32 + lq * 8];
#pragma unroll
    for (int j = 0; j < 4; j++) bb[j] = *(const bf16x8*)&Bs[(wn + j * 16 + lr) * 32 + lq * 8];
#pragma unroll
    for (int i = 0; i < 4; i++)
#pragma unroll
      for (int j = 0; j < 4; j++)
        acc[i][j] = __builtin_amdgcn_mfma_f32_16x16x32_bf16(a[i], bb[j], acc[i][j], 0, 0, 0);
    __syncthreads();
  }
  if (y == 2) {
#pragma unroll
    for (int i = 0; i < 4; i++) {
#pragma unroll
      for (int r = 0; r < 4; r++) {
        int row = mBase + wm + i * 16 + lq * 4 + r;
        if (row < M) {
          float dv = dinv[row];
#pragma unroll
          for (int j = 0; j < 4; j++) {
            int col = wn + j * 16 + lr;
            C2g[(size_t)row * 128 + col] = f32_to_fp8(dv * acc[i][j][r]);
          }
        }
      }
    }
  } else {
    bf16* __restrict__ C = y ? C1 : C0;
#pragma unroll
    for (int i = 0; i < 4; i++) {
#pragma unroll
      for (int r = 0; r < 4; r++) {
        int row = mBase + wm + i * 16 + lq * 4 + r;
        if (row < M) {
#pragma unroll
          for (int j = 0; j < 4; j++) {
            int col = wn + j * 16 + lr;
            C[(size_t)row * 128 + col] = (bf16)acc[i][j][r];
          }
        }
      }
    }
  }
}

// fp8 row-major [N][128] -> fp4 [N][64B] with x2 prescale
__global__ void cvt48_k(const u8* __restrict__ g8, u8* __restrict__ g4) {
  int i = blockIdx.x * 256 + threadIdx.x;
  if (i >= N_NODES * 16) return;
  int n = i >> 4, j = i & 15;
  uint2 w = *(const uint2*)(g8 + (size_t)n * 128 + j * 8);
  auto a0 = __builtin_amdgcn_cvt_pk_f32_fp8((int)w.x, false);
  auto a1 = __builtin_amdgcn_cvt_pk_f32_fp8((int)w.x, true);
  auto a2 = __builtin_amdgcn_cvt_pk_f32_fp8((int)w.y, false);
  auto a3 = __builtin_amdgcn_cvt_pk_f32_fp8((int)w.y, true);
  unsigned u = 0;
  u = __builtin_amdgcn_cvt_scalef32_pk_fp4_f32(u, 2.f * a0[0], 2.f * a0[1], 1.f, 0);
  u = __builtin_amdgcn_cvt_scalef32_pk_fp4_f32(u, 2.f * a1[0], 2.f * a1[1], 1.f, 1);
  u = __builtin_amdgcn_cvt_scalef32_pk_fp4_f32(u, 2.f * a2[0], 2.f * a2[1], 1.f, 2);
  u = __builtin_amdgcn_cvt_scalef32_pk_fp4_f32(u, 2.f * a3[0], 2.f * a3[1], 1.f, 3);
  *(unsigned*)(g4 + (size_t)n * 64 + j * 4) = u;
}

// ---------------- fp4 sparse propagation ----------------
// Wave = 1 node. Quarter-wave (16 lanes) per edge; lane j covers features 8j..8j+7
// (dword j of the 64B fp4 row). 32 edges per loop body (8 per quarter): all 8
// gathers issue back-to-back for max memory-level parallelism; next chunk's csr
// prefetched during decode. Packed f32x2 accumulate (v_pk_add_f32).
// Tables store fp4(2 * dinv_src * value); consumer multiplies sums by 0.5.
// MODE 0: t = -0.5*dn*S + addA;          write fp4(2*dn*t) -> out4
// MODE 1: h = relu(-0.5*dn*S + addA + bias); fused V = h @ wlcT -> V0,V1,V2s
template <int MODE>
__global__ __launch_bounds__(256) void prop_k(const int* __restrict__ rowptr,
                                              const int* __restrict__ csr,
                                              const u8* __restrict__ g4,
                                              const float* __restrict__ dinv,
                                              const bf16* __restrict__ addA,
                                              const float* __restrict__ bias,
                                              const float* __restrict__ wlc,
                                              u8* __restrict__ out4,
                                              f32x2* __restrict__ V0,
                                              f32x2* __restrict__ V1,
                                              f32x2* __restrict__ V2s) {
  const int n = blockIdx.x * 4 + (threadIdx.x >> 6);
  const int lane = threadIdx.x & 63;
  const int qq = lane >> 4, j = lane & 15;
  const int beg = rowptr[n], end = rowptr[n + 1];
  const unsigned jb = (unsigned)j << 2;  // byte offset of dword j within a 64B row

  // hoisted per-node loads: latency overlaps the gather loop
  const float dn = dinv[n];
  uint4 ua = *(const uint4*)(addA + (size_t)n * 128 + j * 8);
  f32x4 bq0, bq1;
  if (MODE == 1) {
    bq0 = *(const f32x4*)(bias + 8 * j);
    bq1 = *(const f32x4*)(bias + 8 * j + 4);
  }

  f32x2 av[4] = {};  // packed accumulators: av[k] = {feat 8j+2k, feat 8j+2k+1}

  // prefetch csr chunk 0 (32 edges: 8 per quarter)
  int c[8];
#pragma unroll
  for (int u = 0; u < 8; u++) {
    int iu = beg + 4 * u + qq;
    c[u] = (iu < end) ? csr[iu] : N_NODES;  // pad row = zeros
  }
  for (int e0 = beg; e0 < end; e0 += 32) {
    // all 8 gathers issue back-to-back (uniform SGPR base + 32-bit voffset)
    unsigned w[8];
#pragma unroll
    for (int u = 0; u < 8; u++)
      w[u] = *(const unsigned*)(g4 + (((unsigned)c[u] << 6) | jb));
    // prefetch next chunk's csr (independent of gathers)
#pragma unroll
    for (int u = 0; u < 8; u++) {
      int iu = e0 + 32 + 4 * u + qq;
      c[u] = (iu < end) ? csr[iu] : N_NODES;
    }
    // decode + packed accumulate: 4 cvt + 4 v_pk_add_f32 per dword
#pragma unroll
    for (int u = 0; u < 8; u++) {
      av[0] += __builtin_amdgcn_cvt_scalef32_pk_f32_fp4(w[u], 1.f, 0);
      av[1] += __builtin_amdgcn_cvt_scalef32_pk_f32_fp4(w[u], 1.f, 1);
      av[2] += __builtin_amdgcn_cvt_scalef32_pk_f32_fp4(w[u], 1.f, 2);
      av[3] += __builtin_amdgcn_cvt_scalef32_pk_f32_fp4(w[u], 1.f, 3);
    }
  }
  // reduce the 4 quarters: lanes 0..15 (qq==0) end up with full sums
#pragma unroll
  for (int off = 32; off >= 16; off >>= 1) {
#pragma unroll
    for (int k = 0; k < 4; k++) {
      av[k].x += __shfl_down(av[k].x, off);
      av[k].y += __shfl_down(av[k].y, off);
    }
  }

  // per-node additive terms: 8 bf16 at features 8j..8j+7, packed pairs
  f32x2 yv[4];
  yv[0].x = bfu(ua.x & 0xffffu); yv[0].y = bfu(ua.x >> 16);
  yv[1].x = bfu(ua.y & 0xffffu); yv[1].y = bfu(ua.y >> 16);
  yv[2].x = bfu(ua.z & 0xffffu); yv[2].y = bfu(ua.z >> 16);
  yv[3].x = bfu(ua.w & 0xffffu); yv[3].y = bfu(ua.w >> 16);

  if (MODE == 0) {
    if (qq == 0) {
      // out = fp4(2dn * (-0.5dn*a + y)) = fp4(a*(-dn^2) + y*(2dn))
      const float m1 = -dn * dn, m2 = 2.f * dn;
      f32x2 ov[4];
#pragma unroll
      for (int k = 0; k < 4; k++) ov[k] = av[k] * m1 + yv[k] * m2;
      unsigned u = 0;
      u = __builtin_amdgcn_cvt_scalef32_pk_fp4_f32(u, ov[0].x, ov[0].y, 1.f, 0);
      u = __builtin_amdgcn_cvt_scalef32_pk_fp4_f32(u, ov[1].x, ov[1].y, 1.f, 1);
      u = __builtin_amdgcn_cvt_scalef32_pk_fp4_f32(u, ov[2].x, ov[2].y, 1.f, 2);
      u = __builtin_amdgcn_cvt_scalef32_pk_fp4_f32(u, ov[3].x, ov[3].y, 1.f, 3);
      *(unsigned*)(out4 + (size_t)n * 64 + j * 4) = u;
    }
  } else {
    // t = -0.5dn*a + y; h = relu(t + bias); V = h @ wlcT, all in packed pairs.
    // (lanes >=16 compute garbage, discarded by the 16-lane reduce + lane==0 write)
    const float s = -0.5f * dn;
    f32x2 hv[4];
#pragma unroll
    for (int k = 0; k < 4; k++) {
      f32x2 t = av[k] * s + yv[k];
      f32x2 bb; bb.x = bq0[0], bb.y = bq0[1];
      if (k == 1) { bb.x = bq0[2]; bb.y = bq0[3]; }
      if (k == 2) { bb.x = bq1[0]; bb.y = bq1[1]; }
      if (k == 3) { bb.x = bq1[2]; bb.y = bq1[3]; }
      t += bb;
      hv[k].x = fmaxf(t.x, 0.f);
      hv[k].y = fmaxf(t.y, 0.f);
    }
    float p[6];
#pragma unroll
    for (int c2 = 0; c2 < 6; c2++) {
      f32x4 wa = *(const f32x4*)(wlc + c2 * 128 + 8 * j);
      f32x4 wb = *(const f32x4*)(wlc + c2 * 128 + 8 * j + 4);
      f32x2 w0; w0.x = wa[0]; w0.y = wa[1];
      f32x2 w1; w1.x = wa[2]; w1.y = wa[3];
      f32x2 w2; w2.x = wb[0]; w2.y = wb[1];
      f32x2 w3; w3.x = wb[2]; w3.y = wb[3];
      f32x2 acc = hv[0] * w0;
      acc += hv[1] * w1;
      acc += hv[2] * w2;
      acc += hv[3] * w3;
      p[c2] = acc.x + acc.y;
    }
#pragma unroll
    for (int off = 8; off >= 1; off >>= 1)
#pragma unroll
      for (int c2 = 0; c2 < 6; c2++) p[c2] += __shfl_down(p[c2], off);
    if (lane == 0) {
      f32x2 v0, v1, v2;
      v0.x = p[0]; v0.y = p[1];
      v1.x = p[2]; v1.y = p[3];
      v2.x = dn * p[4]; v2.y = dn * p[5];
      V0[n] = v0; V1[n] = v1; V2s[n] = v2;
    }
  }
}

// tiny 2-feature props. 16 lanes per node (16 nodes per 256-thr block) --
// lane-efficient for mean degree ~16 (the old 64-lane/node left 75% idle).
// MODE 0: tW[n] = dn * (-dn * sum(V2s[src]) + V1[n])
// MODE 1: z = -dn * sum(tW[src]) + V0[n] + cc; logits = log_softmax(z)
template <int MODE>
__global__ __launch_bounds__(256) void propT_k(const int* __restrict__ rowptr,
                                               const int* __restrict__ csr,
                                               const f32x2* __restrict__ gsrc,
                                               const float* __restrict__ dinv,
                                               const f32x2* __restrict__ addv,
                                               const float* __restrict__ cc,
                                               f32x2* __restrict__ outv,
                                               float* __restrict__ fout) {
  int n = blockIdx.x * 16 + (threadIdx.x >> 4);
  int l = threadIdx.x & 15;
  int beg = rowptr[n], end = rowptr[n + 1];
  float s0 = 0.f, s1 = 0.f;
  for (int idx = beg + l; idx < end; idx += 16) {
    f32x2 v = gsrc[csr[idx]];
    s0 += v.x;
    s1 += v.y;
  }
  // 16-lane tree reduce: lane (l==0 of each group) accumulates only in-group
  // subtrees (sources at lanes +8,+4,+2,+1 carry in-group partials when consumed)
#pragma unroll
  for (int off = 8; off > 0; off >>= 1) {
    s0 += __shfl_down(s0, off);
    s1 += __shfl_down(s1, off);
  }
  if (l != 0) return;
  float dn = dinv[n];
  f32x2 av = addv[n];
  if (MODE == 0) {
    f32x2 t;
    t.x = dn * (-dn * s0 + av.x);
    t.y = dn * (-dn * s1 + av.y);
    outv[n] = t;
  } else {
    float z0 = -dn * s0 + av.x + cc[0];
    float z1 = -dn * s1 + av.y + cc[1];
    float m = fmaxf(z0, z1);
    float lse = m + logf(expf(z0 - m) + expf(z1 - m));
    fout[(size_t)n * 2 + 0] = z0 - lse;
    fout[(size_t)n * 2 + 1] = z1 - lse;
  }
}

// ---------------- launch ----------------

extern "C" void kernel_launch(void* const* d_in, const int* in_sizes, int n_in,
                              void* d_out, int out_size, void* d_ws, size_t ws_size,
                              hipStream_t stream) {
  const float* x = (const float*)d_in[0];
  const int* ei = (const int*)d_in[1];
  const float* W1 = (const float*)d_in[2];
  const float* b1 = (const float*)d_in[3];
  const float* W2 = (const float*)d_in[4];
  const float* b2 = (const float*)d_in[5];
  const float* Wl = (const float*)d_in[6];
  const float* bl = (const float*)d_in[7];
  float* outp = (float*)d_out;

  const int N = N_NODES;
  const int E = in_sizes[1] / 2;
  const int L = NB * NBLK;          // 125120
  const int L2 = 2 * L;             // concatenated dst||src counts
  const int nChunkS = cdiv(L2, 1024);  // 245 <= 256

  char* ws = (char*)d_ws;
  size_t off = 0;
  auto alloc = [&](size_t bytes) {
    off = (off + 255) & ~(size_t)255;
    size_t o = off;
    off += bytes;
    return o;
  };
  int* flag = (int*)(ws + alloc(4));
  int* gcAll = (int*)(ws + alloc((size_t)L2 * 4));  // gcd | gcs (adjacent!)
  int* bsum = (int*)(ws + alloc(1024));
  int* grand = (int*)(ws + alloc(4));
  int* rowptr = (int*)(ws + alloc((size_t)(N + 1) * 4));
  float* dinv = (float*)(ws + alloc((size_t)N * 4));
  unsigned* pkAll = (unsigned*)(ws + alloc((size_t)2 * E * 4));
  int* csr = (int*)(ws + alloc((size_t)E * 4));
  bf16* wct1 = (bf16*)(ws + alloc((size_t)384 * 192 * 2));
  float* wlc = (float*)(ws + alloc((size_t)128 * 6 * 4));
  float* cc = (float*)(ws + alloc(8));
  bf16* xp = (bf16*)(ws + alloc((size_t)N * 192 * 2));
  bf16* U0 = (bf16*)(ws + alloc((size_t)N * 128 * 2));
  bf16* U1 = (bf16*)(ws + alloc((size_t)N * 128 * 2));
  u8* G8 = (u8*)(ws + alloc((size_t)N * 128));          // fp8 gemm slab-2 out
  u8* G0 = (u8*)(ws + alloc((size_t)(N + 1) * 64));     // fp4 tables
  u8* G1 = (u8*)(ws + alloc((size_t)(N + 1) * 64));
  f32x2* V0 = (f32x2*)(ws + alloc((size_t)N * 8));
  f32x2* V1 = (f32x2*)(ws + alloc((size_t)N * 8));
  f32x2* V2s = (f32x2*)(ws + alloc((size_t)N * 8));
  f32x2* tW = (f32x2*)(ws + alloc((size_t)N * 8));
  (void)ws_size;

  int* gcd = gcAll;
  int* gcs = gcAll + L;

  hipMemsetAsync(flag, 0, 4, stream);
  detect_k<<<256, 256, 0, stream>>>(ei, flag);

  // ---- bucket-sort CSR + degree (one concatenated scan) ----
  hist_k<<<NBLK, 256, 0, stream>>>(ei, E, flag, gcd, gcs);
  scanA_k<<<nChunkS, 256, 0, stream>>>(gcAll, bsum, L2);
  scanB_k<<<1, 256, 0, stream>>>(bsum, grand, nChunkS);
  scanC_k<<<nChunkS, 256, 0, stream>>>(gcAll, bsum, gcAll, L2);
  // scatter + fused float edge-copy into output region
  scat2_k<<<NBLK, 256, 0, stream>>>(ei, E, flag, gcd, gcs, pkAll,
                                    outp + (size_t)2 * N);
  fin_dst_k<<<NB, 256, 0, stream>>>(pkAll, gcd, gcAll + L, rowptr, csr);
  fin_src_k<<<NB, 256, 0, stream>>>(pkAll, gcs, grand, dinv);

  prep_k<<<1, 256, 0, stream>>>(W2, Wl, b2, bl, wlc, cc, G0, G1);
  pad_x_k<<<cdiv(N * 96, 256), 256, 0, stream>>>(x, xp);
  build_wct_k<<<cdiv(384 * 192, 256), 256, 0, stream>>>(W1, wct1, F_IN, 192);

  const int gm = cdiv(N, 128);
  const int gmp = cdiv(gm, 8) * 8;  // pad so xcd co-schedule decode is bijective
  // layer 1: Y0 -> U0 (bf16), Y1 -> U1 (bf16), Y2 -> G8 (fp8, dinv-scaled)
  gemm3_k<<<gmp * 3, 256, 0, stream>>>(xp, 192, wct1, 192, U0, U1, G8, dinv, N);
  cvt48_k<<<cdiv(N * 16, 256), 256, 0, stream>>>(G8, G0);
  // A1 (fp4) = dinv*(P(Y2)+Y1): gather G0, add U1 -> G1
  prop_k<0><<<N / 4, 256, 0, stream>>>(rowptr, csr, G0, dinv, U1, nullptr, nullptr,
                                       G1, nullptr, nullptr, nullptr);
  // h = relu(P(A1)+Y0+b1) fused with V = h@wlcT
  prop_k<1><<<N / 4, 256, 0, stream>>>(rowptr, csr, G1, dinv, U0, b1, wlc,
                                       nullptr, V0, V1, V2s);
  // tW = dinv * (P(v2) + v1)
  propT_k<0><<<N / 16, 256, 0, stream>>>(rowptr, csr, V2s, dinv, V1, nullptr, tW, nullptr);
  // logits = log_softmax(P(t) + v0 + cc)
  propT_k<1><<<N / 16, 256, 0, stream>>>(rowptr, csr, tW, dinv, V0, cc, nullptr, outp);
}